// Round 1
// baseline (905.046 us; speedup 1.0000x reference)
//
#include <hip/hip_runtime.h>

constexpr int Bn    = 16;
constexpr int Cn    = 256;
constexpr int Hn    = 56;
constexpr int Wn    = 56;
constexpr int HWn   = Hn * Wn;       // 3136
constexpr int NHn   = 8;
constexpr int HDn   = 32;
constexpr int RWn   = 7;             // regions per side
constexpr int NREGn = 49;
constexpr int TOPKn = 4;
constexpr float SCALEf = 0.0625f;    // 256^-0.5

// ---------------------------------------------------------------------------
// GEMM: out[b,m,p] = sum_k Wm[m,k] * in[b,k,p] + bias[m]
// in layout (B, K=256, HW), out layout (B, M, HW). 64x64 tile, 4x4 per thread.
// ---------------------------------------------------------------------------
__global__ __launch_bounds__(256)
void gemm_cmajor(const float* __restrict__ Wm, const float* __restrict__ bias,
                 const float* __restrict__ in, float* __restrict__ out, int M)
{
    constexpr int K = Cn;
    const int b  = blockIdx.z;
    const int m0 = blockIdx.y * 64;
    const int p0 = blockIdx.x * 64;
    __shared__ float As[16][68];   // [k][m], pad 4 keeps 16B align + no conflicts
    __shared__ float Bs[16][68];   // [k][p]
    const int tid = threadIdx.x;
    const int tx = tid & 15, ty = tid >> 4;
    const float* inb = in + (size_t)b * K * HWn;
    float acc[4][4] = {};
    for (int k0 = 0; k0 < K; k0 += 16) {
        {   // A tile: W[m0+r][k0+c4..c4+3] -> As[c][r]
            const int r  = tid >> 2;
            const int c4 = (tid & 3) << 2;
            const float4 av = *(const float4*)(Wm + (size_t)(m0 + r) * K + (k0 + c4));
            As[c4 + 0][r] = av.x;
            As[c4 + 1][r] = av.y;
            As[c4 + 2][r] = av.z;
            As[c4 + 3][r] = av.w;
        }
        {   // B tile: in[k0+r][p0+c4..] -> Bs[r][c]
            const int r  = tid >> 4;
            const int c4 = (tid & 15) << 2;
            const float4 bv = *(const float4*)(inb + (size_t)(k0 + r) * HWn + (p0 + c4));
            *(float4*)&Bs[r][c4] = bv;
        }
        __syncthreads();
        #pragma unroll
        for (int k = 0; k < 16; ++k) {
            const float4 a4 = *(const float4*)&As[k][ty << 2];
            const float4 b4 = *(const float4*)&Bs[k][tx << 2];
            const float av[4] = {a4.x, a4.y, a4.z, a4.w};
            const float bv[4] = {b4.x, b4.y, b4.z, b4.w};
            #pragma unroll
            for (int i = 0; i < 4; ++i)
                #pragma unroll
                for (int j = 0; j < 4; ++j)
                    acc[i][j] = fmaf(av[i], bv[j], acc[i][j]);
        }
        __syncthreads();
    }
    float* ob = out + (size_t)b * M * HWn;
    #pragma unroll
    for (int i = 0; i < 4; ++i) {
        const int m = m0 + (ty << 2) + i;
        const float bb = bias[m];
        float4 o4;
        o4.x = acc[i][0] + bb; o4.y = acc[i][1] + bb;
        o4.z = acc[i][2] + bb; o4.w = acc[i][3] + bb;
        *(float4*)(ob + (size_t)m * HWn + p0 + (tx << 2)) = o4;
    }
}

// ---------------------------------------------------------------------------
// Region 8x8 mean-pool of q (ch 0..255) and k (ch 256..511) planes of qkv.
// qr/kr layout: (B, C, NREG)
// ---------------------------------------------------------------------------
__global__ __launch_bounds__(256)
void pool_qk(const float* __restrict__ qkv, float* __restrict__ qr,
             float* __restrict__ kr)
{
    const int gid = blockIdx.x * 256 + threadIdx.x;
    if (gid >= Bn * 2 * Cn * NREGn) return;
    const int r = gid % NREGn;
    int t = gid / NREGn;
    const int c = t % Cn; t /= Cn;
    const int which = t & 1;
    const int b = t >> 1;
    const int ri = r / RWn, rj = r % RWn;
    const float* plane = qkv + ((size_t)b * 3 * Cn + which * Cn + c) * HWn
                       + (ri * 8) * Wn + rj * 8;
    float s = 0.f;
    #pragma unroll
    for (int p = 0; p < 8; ++p) {
        const float4 a  = *(const float4*)(plane + p * Wn);
        const float4 b4 = *(const float4*)(plane + p * Wn + 4);
        s += a.x + a.y + a.z + a.w + b4.x + b4.y + b4.z + b4.w;
    }
    (which ? kr : qr)[((size_t)b * Cn + c) * NREGn + r] = s * (1.0f / 64.0f);
}

// ---------------------------------------------------------------------------
// Per-batch routing: a[i][j] = sum_c qr[b,c,i]*kr[b,c,j]; top-4 j per i.
// ---------------------------------------------------------------------------
__global__ __launch_bounds__(256)
void routing(const float* __restrict__ qr, const float* __restrict__ kr,
             int* __restrict__ idxo)
{
    const int b = blockIdx.x;
    __shared__ float ksh[Cn][NREGn];        // 50 KB
    __shared__ float ar[NREGn][NREGn + 1];  // ~9.8 KB
    const float* qb = qr + (size_t)b * Cn * NREGn;
    const float* kb = kr + (size_t)b * Cn * NREGn;
    for (int rr = 0; rr < NREGn; ++rr)
        ksh[threadIdx.x][rr] = kb[threadIdx.x * NREGn + rr];
    __syncthreads();
    for (int e = threadIdx.x; e < NREGn * NREGn; e += 256) {
        const int i = e / NREGn, j = e % NREGn;
        float s = 0.f;
        for (int c = 0; c < Cn; ++c)
            s = fmaf(qb[c * NREGn + i], ksh[c][j], s);
        ar[i][j] = s;
    }
    __syncthreads();
    if (threadIdx.x < NREGn) {
        const int i = threadIdx.x;
        float bv0 = -3.0e38f, bv1 = -3.0e38f, bv2 = -3.0e38f, bv3 = -3.0e38f;
        int bi0 = 0, bi1 = 0, bi2 = 0, bi3 = 0;
        for (int j = 0; j < NREGn; ++j) {
            const float v = ar[i][j];
            if (v > bv3) {
                if (v > bv0)      { bv3=bv2; bi3=bi2; bv2=bv1; bi2=bi1; bv1=bv0; bi1=bi0; bv0=v; bi0=j; }
                else if (v > bv1) { bv3=bv2; bi3=bi2; bv2=bv1; bi2=bi1; bv1=v; bi1=j; }
                else if (v > bv2) { bv3=bv2; bi3=bi2; bv2=v; bi2=j; }
                else              { bv3=v; bi3=j; }
            }
        }
        int* o = idxo + ((size_t)b * NREGn + i) * TOPKn;
        o[0] = bi0; o[1] = bi1; o[2] = bi2; o[3] = bi3;
    }
}

// ---------------------------------------------------------------------------
// Attention: one wave per (b, head, query-region). lane = query row (0..63).
// Online softmax over 4 gathered regions, K/V staged per 32-col half in LDS.
// Writes attention output directly in grid layout to y (B, C, HW).
// ---------------------------------------------------------------------------
__global__ __launch_bounds__(64)
void attention(const float* __restrict__ qkv, const int* __restrict__ idxp,
               float* __restrict__ y)
{
    const int r = blockIdx.x;
    const int h = blockIdx.y;
    const int b = blockIdx.z;
    const int lane = threadIdx.x;
    const int ri = r / RWn, rj = r % RWn;
    const int py = ri * 8 + (lane >> 3);
    const int px = rj * 8 + (lane & 7);
    const size_t base = (size_t)b * (3 * Cn) * HWn;

    __shared__ float kbuf[32][36];   // [col][d], pad 4 -> b128-aligned rows
    __shared__ float vbuf[32][36];

    const float* qp = qkv + base + (size_t)(h * HDn) * HWn + py * Wn + px;
    float qreg[32];
    #pragma unroll
    for (int d = 0; d < 32; ++d) qreg[d] = qp[(size_t)d * HWn] * SCALEf;

    float o[32] = {};
    float mrow = -3.0e38f;
    float lrow = 0.f;

    const int s2 = lane & 31;
    const int dbase = (lane >> 5) << 4;   // 0 or 16

    for (int t = 0; t < TOPKn; ++t) {
        const int rr = idxp[((size_t)b * NREGn + r) * TOPKn + t];
        const int rri = rr / RWn, rrj = rr % RWn;
        const float* kp = qkv + base + (size_t)(Cn + h * HDn) * HWn
                        + (rri * 8) * Wn + rrj * 8;
        const float* vp = qkv + base + (size_t)(2 * Cn + h * HDn) * HWn
                        + (rri * 8) * Wn + rrj * 8;
        for (int half = 0; half < 2; ++half) {
            const int sp = half * 32 + s2;
            const int so = (sp >> 3) * Wn + (sp & 7);
            float tk[16], tv[16];
            #pragma unroll
            for (int j = 0; j < 16; ++j) tk[j] = kp[(size_t)(dbase + j) * HWn + so];
            #pragma unroll
            for (int j = 0; j < 16; ++j) tv[j] = vp[(size_t)(dbase + j) * HWn + so];
            __syncthreads();   // prior half's LDS reads done before overwrite
            #pragma unroll
            for (int j = 0; j < 16; ++j) kbuf[s2][dbase + j] = tk[j];
            #pragma unroll
            for (int j = 0; j < 16; ++j) vbuf[s2][dbase + j] = tv[j];
            __syncthreads();

            // S row-slice: 32 cols, dot over d=32 (LDS reads are broadcasts)
            float sv[32];
            #pragma unroll
            for (int u = 0; u < 32; ++u) {
                float a = 0.f;
                #pragma unroll
                for (int d4 = 0; d4 < 8; ++d4) {
                    const float4 k4 = *(const float4*)&kbuf[u][d4 << 2];
                    a = fmaf(qreg[(d4 << 2) + 0], k4.x, a);
                    a = fmaf(qreg[(d4 << 2) + 1], k4.y, a);
                    a = fmaf(qreg[(d4 << 2) + 2], k4.z, a);
                    a = fmaf(qreg[(d4 << 2) + 3], k4.w, a);
                }
                sv[u] = a;
            }
            float mloc = sv[0];
            #pragma unroll
            for (int u = 1; u < 32; ++u) mloc = fmaxf(mloc, sv[u]);
            const float mnew = fmaxf(mrow, mloc);
            const float corr = __expf(mrow - mnew);   // 0 on first block
            mrow = mnew;
            float psum = 0.f;
            #pragma unroll
            for (int u = 0; u < 32; ++u) { sv[u] = __expf(sv[u] - mnew); psum += sv[u]; }
            lrow = lrow * corr + psum;
            #pragma unroll
            for (int d = 0; d < 32; ++d) o[d] *= corr;
            #pragma unroll
            for (int u = 0; u < 32; ++u) {
                const float pu = sv[u];
                #pragma unroll
                for (int d4 = 0; d4 < 8; ++d4) {
                    const float4 v4 = *(const float4*)&vbuf[u][d4 << 2];
                    o[(d4 << 2) + 0] = fmaf(pu, v4.x, o[(d4 << 2) + 0]);
                    o[(d4 << 2) + 1] = fmaf(pu, v4.y, o[(d4 << 2) + 1]);
                    o[(d4 << 2) + 2] = fmaf(pu, v4.z, o[(d4 << 2) + 2]);
                    o[(d4 << 2) + 3] = fmaf(pu, v4.w, o[(d4 << 2) + 3]);
                }
            }
        }
    }
    const float inv = 1.0f / lrow;
    float* yp = y + ((size_t)b * Cn + h * HDn) * HWn + py * Wn + px;
    #pragma unroll
    for (int d = 0; d < 32; ++d) yp[(size_t)d * HWn] = o[d] * inv;
}

// ---------------------------------------------------------------------------
// LePE: depthwise 5x5 SAME conv on v (ch 512..767 of qkv), += into y.
// ---------------------------------------------------------------------------
__global__ __launch_bounds__(256)
void lepe_add(const float* __restrict__ qkv, const float* __restrict__ lw,
              const float* __restrict__ lb, float* __restrict__ y)
{
    const int p = blockIdx.x * 256 + threadIdx.x;
    if (p >= HWn) return;
    const int c = blockIdx.y;
    const int b = blockIdx.z;
    const int yy = p / Wn, xx = p % Wn;
    const float* vp = qkv + ((size_t)b * 3 * Cn + 2 * Cn + c) * HWn;
    const float* wc = lw + c * 25;
    float s = lb[c];
    #pragma unroll
    for (int kh = 0; kh < 5; ++kh) {
        const int iy = yy + kh - 2;
        if (iy < 0 || iy >= Hn) continue;
        const float* rowp = vp + iy * Wn;
        #pragma unroll
        for (int kw = 0; kw < 5; ++kw) {
            const int ix = xx + kw - 2;
            if (ix < 0 || ix >= Wn) continue;
            s = fmaf(rowp[ix], wc[kh * 5 + kw], s);
        }
    }
    y[((size_t)b * Cn + c) * HWn + p] += s;
}

// ---------------------------------------------------------------------------
extern "C" void kernel_launch(void* const* d_in, const int* in_sizes, int n_in,
                              void* d_out, int out_size, void* d_ws, size_t ws_size,
                              hipStream_t stream)
{
    const float* x      = (const float*)d_in[0];
    const float* qkv_w  = (const float*)d_in[1];
    const float* qkv_b  = (const float*)d_in[2];
    const float* lepe_w = (const float*)d_in[3];
    const float* lepe_b = (const float*)d_in[4];
    const float* out_w  = (const float*)d_in[5];
    const float* out_b  = (const float*)d_in[6];
    float* out = (float*)d_out;

    float* qkv = (float*)d_ws;                          // B*768*HW
    float* y   = qkv + (size_t)Bn * 3 * Cn * HWn;       // B*256*HW
    float* qr  = y   + (size_t)Bn * Cn * HWn;           // B*256*49
    float* kr  = qr  + (size_t)Bn * Cn * NREGn;         // B*256*49
    int*  idx  = (int*)(kr + (size_t)Bn * Cn * NREGn);  // B*49*4

    gemm_cmajor<<<dim3(HWn / 64, (3 * Cn) / 64, Bn), 256, 0, stream>>>(
        qkv_w, qkv_b, x, qkv, 3 * Cn);
    pool_qk<<<dim3((Bn * 2 * Cn * NREGn + 255) / 256), 256, 0, stream>>>(qkv, qr, kr);
    routing<<<dim3(Bn), 256, 0, stream>>>(qr, kr, idx);
    attention<<<dim3(NREGn, NHn, Bn), 64, 0, stream>>>(qkv, idx, y);
    lepe_add<<<dim3((HWn + 255) / 256, Cn, Bn), 256, 0, stream>>>(qkv, lepe_w, lepe_b, y);
    gemm_cmajor<<<dim3(HWn / 64, Cn / 64, Bn), 256, 0, stream>>>(
        out_w, out_b, y, out, Cn);
}

// Round 2
// 884.127 us; speedup vs baseline: 1.0237x; 1.0237x over previous
//
#include <hip/hip_runtime.h>

typedef __attribute__((ext_vector_type(8))) short short8;
typedef __attribute__((ext_vector_type(4))) float f32x4;
typedef unsigned int uint;
typedef unsigned short ushort_t;

constexpr int Bn    = 16;
constexpr int Cn    = 256;
constexpr int Hn    = 56;
constexpr int Wn    = 56;
constexpr int HWn   = Hn * Wn;       // 3136
constexpr int NPn   = 3200;          // padded N (25 * 128)
constexpr int NHn   = 8;
constexpr int RWn   = 7;
constexpr int NREGn = 49;
constexpr int TOPKn = 4;
constexpr float SCALEf = 0.0625f;

__device__ __forceinline__ float b2fl(uint u) { return __builtin_bit_cast(float, u << 16); }
__device__ __forceinline__ float b2fh(uint u) { return __builtin_bit_cast(float, u & 0xffff0000u); }
__device__ __forceinline__ float b2f(ushort u) { return __builtin_bit_cast(float, (uint)u << 16); }
__device__ __forceinline__ ushort f2b(float f) {
    uint u = __builtin_bit_cast(uint, f);
    u = (u + 0x7fffu + ((u >> 16) & 1u)) >> 16;
    return (ushort)u;
}

typedef __attribute__((address_space(3))) uint lds_u32_t;
typedef __attribute__((address_space(1))) const uint glb_u32_t;
__device__ __forceinline__ void gl_lds16(const ushort* g, ushort* l) {
    __builtin_amdgcn_global_load_lds((glb_u32_t*)g, (lds_u32_t*)l, 16, 0, 0);
}

// ---------------------------------------------------------------------------
// fill pad rows (3136..3199) of XT and YT with zeros
// ---------------------------------------------------------------------------
__global__ __launch_bounds__(256)
void fill_pads(uint* __restrict__ xt, uint* __restrict__ yt)
{
    const int gid = blockIdx.x * 256 + threadIdx.x;      // 0..262143
    const int arr = gid >> 17;
    const int e   = gid & 131071;
    const int b   = e >> 13;                              // 8192 uints / batch
    const int off = e & 8191;
    uint* base = arr ? yt : xt;
    base[(size_t)b * (NPn * Cn / 2) + (HWn * Cn / 2) + off] = 0u;
}

// ---------------------------------------------------------------------------
// convert qkv_w (768x256) and out_w (256x256) f32 -> bf16
// ---------------------------------------------------------------------------
__global__ __launch_bounds__(256)
void convert_w(const float* __restrict__ qw, const float* __restrict__ ow,
               ushort* __restrict__ wq, ushort* __restrict__ wo)
{
    const int e = (blockIdx.x * 256 + threadIdx.x) * 4;   // 262144 total
    if (e < 196608) {
        const float4 v = *(const float4*)(qw + e);
        *(ushort4*)(wq + e) = make_ushort4(f2b(v.x), f2b(v.y), f2b(v.z), f2b(v.w));
    } else {
        const int e2 = e - 196608;
        const float4 v = *(const float4*)(ow + e2);
        *(ushort4*)(wo + e2) = make_ushort4(f2b(v.x), f2b(v.y), f2b(v.z), f2b(v.w));
    }
}

// ---------------------------------------------------------------------------
// x (B,256,3136) f32 -> XT (B,3200,256) bf16 (transposed, N-major)
// ---------------------------------------------------------------------------
__global__ __launch_bounds__(256)
void convert_x(const float* __restrict__ x, ushort* __restrict__ xt)
{
    __shared__ float tile[64][65];
    const int p0 = blockIdx.x * 64, c0 = blockIdx.y * 64, b = blockIdx.z;
    const int tid = threadIdx.x;
    #pragma unroll
    for (int it = 0; it < 4; ++it) {
        const int slot = it * 256 + tid;
        const int c = slot >> 4, p4 = (slot & 15) << 2;
        const float4 v = *(const float4*)(x + ((size_t)b * Cn + c0 + c) * HWn + p0 + p4);
        tile[c][p4 + 0] = v.x; tile[c][p4 + 1] = v.y;
        tile[c][p4 + 2] = v.z; tile[c][p4 + 3] = v.w;
    }
    __syncthreads();
    #pragma unroll
    for (int it = 0; it < 4; ++it) {
        const int slot = it * 256 + tid;
        const int p = slot >> 4, c4 = (slot & 15) << 2;
        ushort4 w4 = make_ushort4(f2b(tile[c4 + 0][p]), f2b(tile[c4 + 1][p]),
                                  f2b(tile[c4 + 2][p]), f2b(tile[c4 + 3][p]));
        *(ushort4*)(xt + ((size_t)b * NPn + p0 + p) * Cn + c0 + c4) = w4;
    }
}

// ---------------------------------------------------------------------------
// pool x: (B,256,3136) f32 -> xr (B,256,49) f32  (8x8 region means)
// ---------------------------------------------------------------------------
__global__ __launch_bounds__(256)
void pool_x(const float* __restrict__ x, float* __restrict__ xr)
{
    const int gid = blockIdx.x * 256 + threadIdx.x;
    if (gid >= Bn * Cn * NREGn) return;
    const int r = gid % NREGn;
    const int t = gid / NREGn;
    const int c = t % Cn, b = t / Cn;
    const float* plane = x + ((size_t)b * Cn + c) * HWn + (r / RWn) * 8 * Wn + (r % RWn) * 8;
    float s = 0.f;
    #pragma unroll
    for (int p = 0; p < 8; ++p) {
        const float4 a  = *(const float4*)(plane + p * Wn);
        const float4 b4 = *(const float4*)(plane + p * Wn + 4);
        s += a.x + a.y + a.z + a.w + b4.x + b4.y + b4.z + b4.w;
    }
    xr[gid] = s * (1.0f / 64.0f);
}

// ---------------------------------------------------------------------------
// pooled q_r/k_r in f32 from pooled x (pooling commutes with 1x1 conv)
// qr,kr layout (B,256,49)
// ---------------------------------------------------------------------------
__global__ __launch_bounds__(256)
void qkr_gemm(const float* __restrict__ qw, const float* __restrict__ qb,
              const float* __restrict__ xr, float* __restrict__ qr,
              float* __restrict__ kr)
{
    const int m = blockIdx.x * 64 + (threadIdx.x >> 2);   // 0..511
    const int b = blockIdx.y;
    const int jl = threadIdx.x & 3;
    const float* wr = qw + (size_t)m * Cn;
    const float* xb = xr + (size_t)b * Cn * NREGn;
    for (int j = jl; j < NREGn; j += 4) {
        float s = 0.f;
        #pragma unroll 8
        for (int c = 0; c < Cn; ++c)
            s = fmaf(wr[c], xb[c * NREGn + j], s);
        s += qb[m];
        if (m < Cn) qr[((size_t)b * Cn + m) * NREGn + j] = s;
        else        kr[((size_t)b * Cn + (m - Cn)) * NREGn + j] = s;
    }
}

// ---------------------------------------------------------------------------
// routing: a[i][j] = sum_c qr[b,c,i]*kr[b,c,j]; top-4 per row (f32 exact path)
// ---------------------------------------------------------------------------
__global__ __launch_bounds__(256)
void routing(const float* __restrict__ qr, const float* __restrict__ kr,
             int* __restrict__ idxo)
{
    const int b = blockIdx.x;
    __shared__ float ksh[Cn][NREGn];
    __shared__ float ar[NREGn][NREGn + 1];
    const float* qb = qr + (size_t)b * Cn * NREGn;
    const float* kb = kr + (size_t)b * Cn * NREGn;
    for (int rr = 0; rr < NREGn; ++rr)
        ksh[threadIdx.x][rr] = kb[threadIdx.x * NREGn + rr];
    __syncthreads();
    for (int e = threadIdx.x; e < NREGn * NREGn; e += 256) {
        const int i = e / NREGn, j = e % NREGn;
        float s = 0.f;
        for (int c = 0; c < Cn; ++c)
            s = fmaf(qb[c * NREGn + i], ksh[c][j], s);
        ar[i][j] = s;
    }
    __syncthreads();
    if (threadIdx.x < NREGn) {
        const int i = threadIdx.x;
        float bv0 = -3.0e38f, bv1 = -3.0e38f, bv2 = -3.0e38f, bv3 = -3.0e38f;
        int bi0 = 0, bi1 = 0, bi2 = 0, bi3 = 0;
        for (int j = 0; j < NREGn; ++j) {
            const float v = ar[i][j];
            if (v > bv3) {
                if (v > bv0)      { bv3=bv2; bi3=bi2; bv2=bv1; bi2=bi1; bv1=bv0; bi1=bi0; bv0=v; bi0=j; }
                else if (v > bv1) { bv3=bv2; bi3=bi2; bv2=bv1; bi2=bi1; bv1=v; bi1=j; }
                else if (v > bv2) { bv3=bv2; bi3=bi2; bv2=v; bi2=j; }
                else              { bv3=v; bi3=j; }
            }
        }
        int* o = idxo + ((size_t)b * NREGn + i) * TOPKn;
        o[0] = bi0; o[1] = bi1; o[2] = bi2; o[3] = bi3;
    }
}

// ---------------------------------------------------------------------------
// bf16 MFMA GEMM: D[m][n] = sum_k W[m][k] * XT[n][k], 128x128 tile, 4 waves.
// MODE 0: qkv projection -> q/k/v seq layout (B,NH,3136,32) bf16 + v plane bf16
// MODE 1: out projection -> d_out f32 plane (B,256,HW), n is region-ordered
// ---------------------------------------------------------------------------
template<int MODE>
__global__ __launch_bounds__(256)
void gemm_mfma(const ushort* __restrict__ Wb, const float* __restrict__ bias,
               const ushort* __restrict__ Bt,
               ushort* __restrict__ oq, ushort* __restrict__ ok,
               ushort* __restrict__ ov, ushort* __restrict__ ovp,
               float* __restrict__ of)
{
    constexpr int K = Cn;
    const int bb = blockIdx.z;
    const int n0 = blockIdx.x * 128;
    const int m0 = blockIdx.y * 128;
    __shared__ ushort As[128 * 32];
    __shared__ ushort Bs[128 * 32];
    const int tid = threadIdx.x;
    const int wid = tid >> 6, lane = tid & 63;
    const int wm = wid >> 1, wn = wid & 1;        // wave quadrant (2x2 of 64x64)
    const ushort* Bb = Bt + (size_t)bb * NPn * K;

    f32x4 acc[4][4];
    #pragma unroll
    for (int i = 0; i < 4; ++i)
        #pragma unroll
        for (int j = 0; j < 4; ++j)
            acc[i][j] = (f32x4){0.f, 0.f, 0.f, 0.f};

    const int cA = wid * 64 + lane;               // chunk id 0..255
    const int rowA = cA >> 2, koffA = (cA & 3) << 3;

    for (int k0 = 0; k0 < K; k0 += 32) {
        gl_lds16(Wb + (size_t)(m0 + rowA) * K + k0 + koffA, As + wid * 512);
        gl_lds16(Wb + (size_t)(m0 + rowA + 64) * K + k0 + koffA, As + 2048 + wid * 512);
        gl_lds16(Bb + (size_t)(n0 + rowA) * K + k0 + koffA, Bs + wid * 512);
        gl_lds16(Bb + (size_t)(n0 + rowA + 64) * K + k0 + koffA, Bs + 2048 + wid * 512);
        __syncthreads();
        short8 a[4], b[4];
        #pragma unroll
        for (int i = 0; i < 4; ++i)
            a[i] = *(const short8*)(As + (wm * 64 + i * 16 + (lane & 15)) * 32 + ((lane >> 4) << 3));
        #pragma unroll
        for (int j = 0; j < 4; ++j)
            b[j] = *(const short8*)(Bs + (wn * 64 + j * 16 + (lane & 15)) * 32 + ((lane >> 4) << 3));
        #pragma unroll
        for (int i = 0; i < 4; ++i)
            #pragma unroll
            for (int j = 0; j < 4; ++j)
                acc[i][j] = __builtin_amdgcn_mfma_f32_16x16x32_bf16(a[i], b[j], acc[i][j], 0, 0, 0);
        __syncthreads();
    }

    if (MODE == 0) {
        #pragma unroll
        for (int i = 0; i < 4; ++i) {
            const int m_base = m0 + wm * 64 + i * 16;
            const int which = m_base >> 8;                       // 0=q 1=k 2=v
            const int hh = (m_base >> 5) & 7;
            const int db = (m_base & 31) + ((lane >> 4) << 2);   // 0..28
            const int cb = (m_base & 255) + ((lane >> 4) << 2);
            const float4 b4 = *(const float4*)(bias + m_base + ((lane >> 4) << 2));
            ushort* op = (which == 0) ? oq : ((which == 1) ? ok : ov);
            #pragma unroll
            for (int j = 0; j < 4; ++j) {
                const int n = n0 + wn * 64 + j * 16 + (lane & 15);
                if (n < HWn) {
                    const int py = n / 56, px = n % 56;
                    const int rr = (py >> 3) * 7 + (px >> 3);
                    const int ss = ((py & 7) << 3) + (px & 7);
                    ushort4 w4 = make_ushort4(f2b(acc[i][j][0] + b4.x), f2b(acc[i][j][1] + b4.y),
                                              f2b(acc[i][j][2] + b4.z), f2b(acc[i][j][3] + b4.w));
                    *(ushort4*)(op + (((size_t)bb * NHn + hh) * HWn + rr * 64 + ss) * 32 + db) = w4;
                    if (which == 2) {
                        ovp[((size_t)bb * Cn + cb + 0) * HWn + n] = w4.x;
                        ovp[((size_t)bb * Cn + cb + 1) * HWn + n] = w4.y;
                        ovp[((size_t)bb * Cn + cb + 2) * HWn + n] = w4.z;
                        ovp[((size_t)bb * Cn + cb + 3) * HWn + n] = w4.w;
                    }
                }
            }
        }
    } else {
        #pragma unroll
        for (int i = 0; i < 4; ++i) {
            const int mb = m0 + wm * 64 + i * 16 + ((lane >> 4) << 2);
            const float4 b4 = *(const float4*)(bias + mb);
            #pragma unroll
            for (int j = 0; j < 4; ++j) {
                const int n = n0 + wn * 64 + j * 16 + (lane & 15);
                if (n < HWn) {
                    const int rr = n >> 6, ss = n & 63;
                    const int py = (rr / 7) * 8 + (ss >> 3);
                    const int px = (rr % 7) * 8 + (ss & 7);
                    float* od = of + ((size_t)bb * Cn + mb) * HWn + py * 56 + px;
                    od[0 * HWn] = acc[i][j][0] + b4.x;
                    od[1 * HWn] = acc[i][j][1] + b4.y;
                    od[2 * HWn] = acc[i][j][2] + b4.z;
                    od[3 * HWn] = acc[i][j][3] + b4.w;
                }
            }
        }
    }
}

// ---------------------------------------------------------------------------
// LePE: depthwise 5x5 SAME conv on v plane (bf16) -> lepe_buf plane (bf16)
// ---------------------------------------------------------------------------
__global__ __launch_bounds__(256)
void lepe(const ushort* __restrict__ vpl, const float* __restrict__ lw,
          const float* __restrict__ lb, ushort* __restrict__ lbuf)
{
    const int t = threadIdx.x;
    if (t >= 224) return;
    const int c = blockIdx.y, b = blockIdx.z;
    const int py = blockIdx.x * 4 + t / 56, px = t % 56;
    const ushort* vp = vpl + ((size_t)b * Cn + c) * HWn;
    const float* wc = lw + c * 25;
    float s = lb[c];
    #pragma unroll
    for (int kh = 0; kh < 5; ++kh) {
        const int iy = py + kh - 2;
        if (iy < 0 || iy >= Hn) continue;
        #pragma unroll
        for (int kw = 0; kw < 5; ++kw) {
            const int ix = px + kw - 2;
            if (ix < 0 || ix >= Wn) continue;
            s = fmaf(b2f(vp[iy * Wn + ix]), wc[kh * 5 + kw], s);
        }
    }
    lbuf[((size_t)b * Cn + c) * HWn + py * Wn + px] = f2b(s);
}

// ---------------------------------------------------------------------------
// Attention: 2 waves/block, wave = one head; lane = query row within region.
// Coalesced seq-layout loads, K/V unpacked to f32 in LDS (broadcast reads).
// Fuses LePE add; writes y_t (B,3200,256) bf16, rows region-ordered.
// ---------------------------------------------------------------------------
__device__ __forceinline__ void st8(uint4 w, float* dst)
{
    float4 a, b;
    a.x = b2fl(w.x); a.y = b2fh(w.x); a.z = b2fl(w.y); a.w = b2fh(w.y);
    b.x = b2fl(w.z); b.y = b2fh(w.z); b.z = b2fl(w.w); b.w = b2fh(w.w);
    *(float4*)(dst)     = a;
    *(float4*)(dst + 4) = b;
}

__global__ __launch_bounds__(128)
void attention2(const ushort* __restrict__ qs, const ushort* __restrict__ ks,
                const ushort* __restrict__ vs, const int* __restrict__ idxp,
                const ushort* __restrict__ lep, ushort* __restrict__ yt)
{
    const int r = blockIdx.x, b = blockIdx.z;
    const int wid = threadIdx.x >> 6, lane = threadIdx.x & 63;
    const int h = blockIdx.y * 2 + wid;
    __shared__ float kb[2][64][36];
    __shared__ float vb[2][64][36];
    const size_t hb = ((size_t)b * NHn + h) * HWn;

    float qreg[32];
    {
        const uint4* qp = (const uint4*)(qs + (hb + r * 64 + lane) * 32);
        st8(qp[0], qreg); st8(qp[1], qreg + 8); st8(qp[2], qreg + 16); st8(qp[3], qreg + 24);
        #pragma unroll
        for (int d = 0; d < 32; ++d) qreg[d] *= SCALEf;
    }

    float o[32];
    #pragma unroll
    for (int d = 0; d < 32; ++d) o[d] = 0.f;
    float mrow = -3.0e38f, lrow = 0.f;

    for (int t = 0; t < TOPKn; ++t) {
        const int rr = idxp[((size_t)b * NREGn + r) * TOPKn + t];
        const uint4* kp = (const uint4*)(ks + (hb + rr * 64 + lane) * 32);
        const uint4* vp = (const uint4*)(vs + (hb + rr * 64 + lane) * 32);
        const uint4 ka = kp[0], kbv = kp[1], kc = kp[2], kd = kp[3];
        const uint4 va = vp[0], vbv = vp[1], vc = vp[2], vd = vp[3];
        __syncthreads();   // prior region's LDS reads done before overwrite
        st8(ka, &kb[wid][lane][0]);  st8(kbv, &kb[wid][lane][8]);
        st8(kc, &kb[wid][lane][16]); st8(kd, &kb[wid][lane][24]);
        st8(va, &vb[wid][lane][0]);  st8(vbv, &vb[wid][lane][8]);
        st8(vc, &vb[wid][lane][16]); st8(vd, &vb[wid][lane][24]);
        __syncthreads();

        #pragma unroll
        for (int uh = 0; uh < 2; ++uh) {
            float sv[32];
            #pragma unroll
            for (int u = 0; u < 32; ++u) {
                const float* krow = &kb[wid][uh * 32 + u][0];
                float s = 0.f;
                #pragma unroll
                for (int d4 = 0; d4 < 8; ++d4) {
                    const float4 k4 = *(const float4*)(krow + (d4 << 2));
                    s = fmaf(qreg[(d4 << 2) + 0], k4.x, s);
                    s = fmaf(qreg[(d4 << 2) + 1], k4.y, s);
                    s = fmaf(qreg[(d4 << 2) + 2], k4.z, s);
                    s = fmaf(qreg[(d4 << 2) + 3], k4.w, s);
                }
                sv[u] = s;
            }
            float mloc = sv[0];
            #pragma unroll
            for (int u = 1; u < 32; ++u) mloc = fmaxf(mloc, sv[u]);
            const float mnew = fmaxf(mrow, mloc);
            const float corr = __expf(mrow - mnew);
            mrow = mnew;
            float ps = 0.f;
            #pragma unroll
            for (int u = 0; u < 32; ++u) { sv[u] = __expf(sv[u] - mnew); ps += sv[u]; }
            lrow = lrow * corr + ps;
            #pragma unroll
            for (int d = 0; d < 32; ++d) o[d] *= corr;
            #pragma unroll
            for (int u = 0; u < 32; ++u) {
                const float pu = sv[u];
                const float* vrow = &vb[wid][uh * 32 + u][0];
                #pragma unroll
                for (int d4 = 0; d4 < 8; ++d4) {
                    const float4 v4 = *(const float4*)(vrow + (d4 << 2));
                    o[(d4 << 2) + 0] = fmaf(pu, v4.x, o[(d4 << 2) + 0]);
                    o[(d4 << 2) + 1] = fmaf(pu, v4.y, o[(d4 << 2) + 1]);
                    o[(d4 << 2) + 2] = fmaf(pu, v4.z, o[(d4 << 2) + 2]);
                    o[(d4 << 2) + 3] = fmaf(pu, v4.w, o[(d4 << 2) + 3]);
                }
            }
        }
    }

    const float inv = 1.0f / lrow;
    const int py = (r / 7) * 8 + (lane >> 3), px = (r % 7) * 8 + (lane & 7);
    const ushort* lp = lep + ((size_t)b * Cn + h * 32) * HWn + py * Wn + px;
    ushort* yp = yt + ((size_t)b * NPn + r * 64 + lane) * Cn + h * 32;
    #pragma unroll
    for (int k = 0; k < 8; ++k) {
        ushort4 w4 = make_ushort4(
            f2b(o[k * 4 + 0] * inv + b2f(lp[(size_t)(k * 4 + 0) * HWn])),
            f2b(o[k * 4 + 1] * inv + b2f(lp[(size_t)(k * 4 + 1) * HWn])),
            f2b(o[k * 4 + 2] * inv + b2f(lp[(size_t)(k * 4 + 2) * HWn])),
            f2b(o[k * 4 + 3] * inv + b2f(lp[(size_t)(k * 4 + 3) * HWn])));
        *(ushort4*)(yp + k * 4) = w4;
    }
}

// ---------------------------------------------------------------------------
extern "C" void kernel_launch(void* const* d_in, const int* in_sizes, int n_in,
                              void* d_out, int out_size, void* d_ws, size_t ws_size,
                              hipStream_t stream)
{
    const float* x      = (const float*)d_in[0];
    const float* qkv_w  = (const float*)d_in[1];
    const float* qkv_b  = (const float*)d_in[2];
    const float* lepe_w = (const float*)d_in[3];
    const float* lepe_b = (const float*)d_in[4];
    const float* out_w  = (const float*)d_in[5];
    const float* out_b  = (const float*)d_in[6];
    float* out = (float*)d_out;

    char* ws = (char*)d_ws;
    ushort* XT = (ushort*)(ws);                                  // 26,214,400
    ushort* YT = (ushort*)(ws + 26214400);                       // 26,214,400
    ushort* QS = (ushort*)(ws + 52428800);                       // 25,690,112
    ushort* KS = (ushort*)(ws + 78118912);                       // 25,690,112
    ushort* VS = (ushort*)(ws + 103809024);                      // 25,690,112
    ushort* VP = (ushort*)(ws + 129499136);                      // 25,690,112
    ushort* LB = (ushort*)(ws + 155189248);                      // 25,690,112
    ushort* WQ = (ushort*)(ws + 180879360);                      // 393,216
    ushort* WO = (ushort*)(ws + 181272576);                      // 131,072
    float*  XR = (float*)(ws + 181403648);                       // 802,816
    float*  QR = (float*)(ws + 182206464);                       // 802,816
    float*  KR = (float*)(ws + 183009280);                       // 802,816
    int*   IDX = (int*)(ws + 183812096);                         // 12,544

    fill_pads<<<1024, 256, 0, stream>>>((uint*)XT, (uint*)YT);
    convert_w<<<256, 256, 0, stream>>>(qkv_w, out_w, WQ, WO);
    convert_x<<<dim3(49, 4, 16), 256, 0, stream>>>(x, XT);
    pool_x<<<(Bn * Cn * NREGn + 255) / 256, 256, 0, stream>>>(x, XR);
    qkr_gemm<<<dim3(8, 16), 256, 0, stream>>>(qkv_w, qkv_b, XR, QR, KR);
    routing<<<16, 256, 0, stream>>>(QR, KR, IDX);
    gemm_mfma<0><<<dim3(25, 6, 16), 256, 0, stream>>>(WQ, qkv_b, XT, QS, KS, VS, VP, nullptr);
    lepe<<<dim3(14, 256, 16), 256, 0, stream>>>(VP, lepe_w, lepe_b, LB);
    attention2<<<dim3(49, 4, 16), 128, 0, stream>>>(QS, KS, VS, IDX, LB, YT);
    gemm_mfma<1><<<dim3(25, 2, 16), 256, 0, stream>>>(WO, out_b, YT, nullptr, nullptr, nullptr, nullptr, out);
}

// Round 3
// 503.530 us; speedup vs baseline: 1.7974x; 1.7559x over previous
//
#include <hip/hip_runtime.h>

typedef __attribute__((ext_vector_type(8))) short short8;
typedef __attribute__((ext_vector_type(4))) float f32x4;
typedef unsigned int uint;

constexpr int Bn    = 16;
constexpr int Cn    = 256;
constexpr int Hn    = 56;
constexpr int Wn    = 56;
constexpr int HWn   = Hn * Wn;       // 3136
constexpr int NPn   = 3200;          // padded N (25 * 128)
constexpr int NHn   = 8;
constexpr int RWn   = 7;
constexpr int NREGn = 49;
constexpr int TOPKn = 4;
constexpr float SCALEf = 0.0625f;

__device__ __forceinline__ float b2f(ushort u) { return __builtin_bit_cast(float, (uint)u << 16); }
__device__ __forceinline__ ushort f2b(float f) {
    uint u = __builtin_bit_cast(uint, f);
    u = (u + 0x7fffu + ((u >> 16) & 1u)) >> 16;
    return (ushort)u;
}

typedef __attribute__((address_space(3))) uint lds_u32_t;
typedef __attribute__((address_space(1))) const uint glb_u32_t;
__device__ __forceinline__ void gl_lds16(const ushort* g, ushort* l) {
    __builtin_amdgcn_global_load_lds((glb_u32_t*)g, (lds_u32_t*)l, 16, 0, 0);
}

// ---------------------------------------------------------------------------
// fill pad rows (3136..3199) of XT and YT with zeros
// ---------------------------------------------------------------------------
__global__ __launch_bounds__(256)
void fill_pads(uint* __restrict__ xt, uint* __restrict__ yt)
{
    const int gid = blockIdx.x * 256 + threadIdx.x;      // 0..262143
    const int arr = gid >> 17;
    const int e   = gid & 131071;
    const int b   = e >> 13;                              // 8192 uints / batch
    const int off = e & 8191;
    uint* base = arr ? yt : xt;
    base[(size_t)b * (NPn * Cn / 2) + (HWn * Cn / 2) + off] = 0u;
}

// ---------------------------------------------------------------------------
// convert qkv_w (768x256) and out_w (256x256) f32 -> bf16
// ---------------------------------------------------------------------------
__global__ __launch_bounds__(256)
void convert_w(const float* __restrict__ qw, const float* __restrict__ ow,
               ushort* __restrict__ wq, ushort* __restrict__ wo)
{
    const int e = (blockIdx.x * 256 + threadIdx.x) * 4;   // 262144 total
    if (e < 196608) {
        const float4 v = *(const float4*)(qw + e);
        *(ushort4*)(wq + e) = make_ushort4(f2b(v.x), f2b(v.y), f2b(v.z), f2b(v.w));
    } else {
        const int e2 = e - 196608;
        const float4 v = *(const float4*)(ow + e2);
        *(ushort4*)(wo + e2) = make_ushort4(f2b(v.x), f2b(v.y), f2b(v.z), f2b(v.w));
    }
}

// ---------------------------------------------------------------------------
// x (B,256,3136) f32 -> XT (B,3200,256) bf16 (transposed, N-major)
// ---------------------------------------------------------------------------
__global__ __launch_bounds__(256)
void convert_x(const float* __restrict__ x, ushort* __restrict__ xt)
{
    __shared__ float tile[64][65];
    const int p0 = blockIdx.x * 64, c0 = blockIdx.y * 64, b = blockIdx.z;
    const int tid = threadIdx.x;
    #pragma unroll
    for (int it = 0; it < 4; ++it) {
        const int slot = it * 256 + tid;
        const int c = slot >> 4, p4 = (slot & 15) << 2;
        const float4 v = *(const float4*)(x + ((size_t)b * Cn + c0 + c) * HWn + p0 + p4);
        tile[c][p4 + 0] = v.x; tile[c][p4 + 1] = v.y;
        tile[c][p4 + 2] = v.z; tile[c][p4 + 3] = v.w;
    }
    __syncthreads();
    #pragma unroll
    for (int it = 0; it < 4; ++it) {
        const int slot = it * 256 + tid;
        const int p = slot >> 4, c4 = (slot & 15) << 2;
        ushort4 w4 = make_ushort4(f2b(tile[c4 + 0][p]), f2b(tile[c4 + 1][p]),
                                  f2b(tile[c4 + 2][p]), f2b(tile[c4 + 3][p]));
        *(ushort4*)(xt + ((size_t)b * NPn + p0 + p) * Cn + c0 + c4) = w4;
    }
}

// ---------------------------------------------------------------------------
// pool x: (B,256,3136) f32 -> xr (B,256,49) f32  (8x8 region means)
// ---------------------------------------------------------------------------
__global__ __launch_bounds__(256)
void pool_x(const float* __restrict__ x, float* __restrict__ xr)
{
    const int gid = blockIdx.x * 256 + threadIdx.x;
    if (gid >= Bn * Cn * NREGn) return;
    const int r = gid % NREGn;
    const int t = gid / NREGn;
    const int c = t % Cn, b = t / Cn;
    const float* plane = x + ((size_t)b * Cn + c) * HWn + (r / RWn) * 8 * Wn + (r % RWn) * 8;
    float s = 0.f;
    #pragma unroll
    for (int p = 0; p < 8; ++p) {
        const float4 a  = *(const float4*)(plane + p * Wn);
        const float4 b4 = *(const float4*)(plane + p * Wn + 4);
        s += a.x + a.y + a.z + a.w + b4.x + b4.y + b4.z + b4.w;
    }
    xr[gid] = s * (1.0f / 64.0f);
}

// ---------------------------------------------------------------------------
// pooled q_r/k_r in f32 from pooled x (pooling commutes with 1x1 conv)
// ---------------------------------------------------------------------------
__global__ __launch_bounds__(256)
void qkr_gemm(const float* __restrict__ qw, const float* __restrict__ qb,
              const float* __restrict__ xr, float* __restrict__ qr,
              float* __restrict__ kr)
{
    const int m = blockIdx.x * 64 + (threadIdx.x >> 2);   // 0..511
    const int b = blockIdx.y;
    const int jl = threadIdx.x & 3;
    const float* wr = qw + (size_t)m * Cn;
    const float* xb = xr + (size_t)b * Cn * NREGn;
    for (int j = jl; j < NREGn; j += 4) {
        float s = 0.f;
        #pragma unroll 8
        for (int c = 0; c < Cn; ++c)
            s = fmaf(wr[c], xb[c * NREGn + j], s);
        s += qb[m];
        if (m < Cn) qr[((size_t)b * Cn + m) * NREGn + j] = s;
        else        kr[((size_t)b * Cn + (m - Cn)) * NREGn + j] = s;
    }
}

// ---------------------------------------------------------------------------
// routing: a[i][j] = sum_c qr[b,c,i]*kr[b,c,j]; top-4 per row (f32 exact path)
// ---------------------------------------------------------------------------
__global__ __launch_bounds__(256)
void routing(const float* __restrict__ qr, const float* __restrict__ kr,
             int* __restrict__ idxo)
{
    const int b = blockIdx.x;
    __shared__ float ksh[Cn][NREGn];
    __shared__ float ar[NREGn][NREGn + 1];
    const float* qb = qr + (size_t)b * Cn * NREGn;
    const float* kb = kr + (size_t)b * Cn * NREGn;
    for (int rr = 0; rr < NREGn; ++rr)
        ksh[threadIdx.x][rr] = kb[threadIdx.x * NREGn + rr];
    __syncthreads();
    for (int e = threadIdx.x; e < NREGn * NREGn; e += 256) {
        const int i = e / NREGn, j = e % NREGn;
        float s = 0.f;
        for (int c = 0; c < Cn; ++c)
            s = fmaf(qb[c * NREGn + i], ksh[c][j], s);
        ar[i][j] = s;
    }
    __syncthreads();
    if (threadIdx.x < NREGn) {
        const int i = threadIdx.x;
        float bv0 = -3.0e38f, bv1 = -3.0e38f, bv2 = -3.0e38f, bv3 = -3.0e38f;
        int bi0 = 0, bi1 = 0, bi2 = 0, bi3 = 0;
        for (int j = 0; j < NREGn; ++j) {
            const float v = ar[i][j];
            if (v > bv3) {
                if (v > bv0)      { bv3=bv2; bi3=bi2; bv2=bv1; bi2=bi1; bv1=bv0; bi1=bi0; bv0=v; bi0=j; }
                else if (v > bv1) { bv3=bv2; bi3=bi2; bv2=bv1; bi2=bi1; bv1=v; bi1=j; }
                else if (v > bv2) { bv3=bv2; bi3=bi2; bv2=v; bi2=j; }
                else              { bv3=v; bi3=j; }
            }
        }
        int* o = idxo + ((size_t)b * NREGn + i) * TOPKn;
        o[0] = bi0; o[1] = bi1; o[2] = bi2; o[3] = bi3;
    }
}

// ---------------------------------------------------------------------------
// bf16 MFMA GEMM: D[m][n] = sum_k W[m][k] * XT[n][k], 128x128 tile, 4 waves.
// MODE 0: qkv -> q/k seq layout (B,NH,3136,32) bf16; v -> VT (B,NH,32,3136)
//         transposed seq + VP plane (B,C,HW) bf16 (for LePE)
// MODE 1: out projection -> d_out f32 plane (B,256,HW), n is region-ordered
// ---------------------------------------------------------------------------
template<int MODE>
__global__ __launch_bounds__(256)
void gemm_mfma(const ushort* __restrict__ Wb, const float* __restrict__ bias,
               const ushort* __restrict__ Bt,
               ushort* __restrict__ oq, ushort* __restrict__ ok,
               ushort* __restrict__ ovt, ushort* __restrict__ ovp,
               float* __restrict__ of)
{
    constexpr int K = Cn;
    const int bb = blockIdx.z;
    const int n0 = blockIdx.x * 128;
    const int m0 = blockIdx.y * 128;
    __shared__ ushort As[128 * 32];
    __shared__ ushort Bs[128 * 32];
    const int tid = threadIdx.x;
    const int wid = tid >> 6, lane = tid & 63;
    const int wm = wid >> 1, wn = wid & 1;        // wave quadrant (2x2 of 64x64)
    const ushort* Bb = Bt + (size_t)bb * NPn * K;

    f32x4 acc[4][4];
    #pragma unroll
    for (int i = 0; i < 4; ++i)
        #pragma unroll
        for (int j = 0; j < 4; ++j)
            acc[i][j] = (f32x4){0.f, 0.f, 0.f, 0.f};

    const int cA = wid * 64 + lane;               // chunk id 0..255
    const int rowA = cA >> 2, koffA = (cA & 3) << 3;

    for (int k0 = 0; k0 < K; k0 += 32) {
        gl_lds16(Wb + (size_t)(m0 + rowA) * K + k0 + koffA, As + wid * 512);
        gl_lds16(Wb + (size_t)(m0 + rowA + 64) * K + k0 + koffA, As + 2048 + wid * 512);
        gl_lds16(Bb + (size_t)(n0 + rowA) * K + k0 + koffA, Bs + wid * 512);
        gl_lds16(Bb + (size_t)(n0 + rowA + 64) * K + k0 + koffA, Bs + 2048 + wid * 512);
        __syncthreads();
        short8 a[4], b[4];
        #pragma unroll
        for (int i = 0; i < 4; ++i)
            a[i] = *(const short8*)(As + (wm * 64 + i * 16 + (lane & 15)) * 32 + ((lane >> 4) << 3));
        #pragma unroll
        for (int j = 0; j < 4; ++j)
            b[j] = *(const short8*)(Bs + (wn * 64 + j * 16 + (lane & 15)) * 32 + ((lane >> 4) << 3));
        #pragma unroll
        for (int i = 0; i < 4; ++i)
            #pragma unroll
            for (int j = 0; j < 4; ++j)
                acc[i][j] = __builtin_amdgcn_mfma_f32_16x16x32_bf16(a[i], b[j], acc[i][j], 0, 0, 0);
        __syncthreads();
    }

    if (MODE == 0) {
        #pragma unroll
        for (int i = 0; i < 4; ++i) {
            const int m_base = m0 + wm * 64 + i * 16;
            const int which = m_base >> 8;                       // 0=q 1=k 2=v
            const int hh = (m_base >> 5) & 7;
            const int db = (m_base & 31) + ((lane >> 4) << 2);   // 0..28
            const int cb = (m_base & 255) + ((lane >> 4) << 2);
            const float4 b4 = *(const float4*)(bias + m_base + ((lane >> 4) << 2));
            #pragma unroll
            for (int j = 0; j < 4; ++j) {
                const int n = n0 + wn * 64 + j * 16 + (lane & 15);
                if (n < HWn) {
                    const int py = n / 56, px = n % 56;
                    const int rr = (py >> 3) * 7 + (px >> 3);
                    const int ss = ((py & 7) << 3) + (px & 7);
                    ushort4 w4 = make_ushort4(f2b(acc[i][j][0] + b4.x), f2b(acc[i][j][1] + b4.y),
                                              f2b(acc[i][j][2] + b4.z), f2b(acc[i][j][3] + b4.w));
                    if (which < 2) {
                        ushort* op = (which == 0) ? oq : ok;
                        *(ushort4*)(op + (((size_t)bb * NHn + hh) * HWn + rr * 64 + ss) * 32 + db) = w4;
                    } else {
                        const size_t vtb = ((size_t)(bb * NHn + hh) * 32 + db) * HWn + rr * 64 + ss;
                        ovt[vtb + 0 * HWn] = w4.x;
                        ovt[vtb + 1 * HWn] = w4.y;
                        ovt[vtb + 2 * HWn] = w4.z;
                        ovt[vtb + 3 * HWn] = w4.w;
                        ovp[((size_t)bb * Cn + cb + 0) * HWn + n] = w4.x;
                        ovp[((size_t)bb * Cn + cb + 1) * HWn + n] = w4.y;
                        ovp[((size_t)bb * Cn + cb + 2) * HWn + n] = w4.z;
                        ovp[((size_t)bb * Cn + cb + 3) * HWn + n] = w4.w;
                    }
                }
            }
        }
    } else {
        #pragma unroll
        for (int i = 0; i < 4; ++i) {
            const int mb = m0 + wm * 64 + i * 16 + ((lane >> 4) << 2);
            const float4 b4 = *(const float4*)(bias + mb);
            #pragma unroll
            for (int j = 0; j < 4; ++j) {
                const int n = n0 + wn * 64 + j * 16 + (lane & 15);
                if (n < HWn) {
                    const int rr = n >> 6, ss = n & 63;
                    const int py = (rr / 7) * 8 + (ss >> 3);
                    const int px = (rr % 7) * 8 + (ss & 7);
                    float* od = of + ((size_t)bb * Cn + mb) * HWn + py * 56 + px;
                    od[0 * HWn] = acc[i][j][0] + b4.x;
                    od[1 * HWn] = acc[i][j][1] + b4.y;
                    od[2 * HWn] = acc[i][j][2] + b4.z;
                    od[3 * HWn] = acc[i][j][3] + b4.w;
                }
            }
        }
    }
}

// ---------------------------------------------------------------------------
// LePE: depthwise 5x5 SAME conv on v plane (bf16) -> lepe_buf plane (bf16)
// ---------------------------------------------------------------------------
__global__ __launch_bounds__(256)
void lepe(const ushort* __restrict__ vpl, const float* __restrict__ lw,
          const float* __restrict__ lb, ushort* __restrict__ lbuf)
{
    const int t = threadIdx.x;
    if (t >= 224) return;
    const int c = blockIdx.y, b = blockIdx.z;
    const int py = blockIdx.x * 4 + t / 56, px = t % 56;
    const ushort* vp = vpl + ((size_t)b * Cn + c) * HWn;
    const float* wc = lw + c * 25;
    float s = lb[c];
    #pragma unroll
    for (int kh = 0; kh < 5; ++kh) {
        const int iy = py + kh - 2;
        if (iy < 0 || iy >= Hn) continue;
        #pragma unroll
        for (int kw = 0; kw < 5; ++kw) {
            const int ix = px + kw - 2;
            if (ix < 0 || ix >= Wn) continue;
            s = fmaf(b2f(vp[iy * Wn + ix]), wc[kh * 5 + kw], s);
        }
    }
    lbuf[((size_t)b * Cn + c) * HWn + py * Wn + px] = f2b(s);
}

// ---------------------------------------------------------------------------
// MFMA attention: 4 waves/block, wave = one (b, head, region). Swapped QK^T
// (S^T = mfma(K,Q)) -> near-lane-local softmax -> P via swizzled LDS bounce
// -> PV with V fragments straight from transposed VT. LePE fused; writes YT.
// ---------------------------------------------------------------------------
__global__ __launch_bounds__(256, 2)
void attention3(const ushort* __restrict__ qs, const ushort* __restrict__ ks,
                const ushort* __restrict__ vt, const int* __restrict__ idxp,
                const ushort* __restrict__ lep, ushort* __restrict__ yt)
{
    const int r = blockIdx.x, b = blockIdx.z;
    const int wid = threadIdx.x >> 6, lane = threadIdx.x & 63;
    const int h = blockIdx.y * 4 + wid;
    const int col = lane & 15, g = lane >> 4;
    __shared__ ushort plds_all[4][4096];          // 8KB per wave
    ushort* pw = plds_all[wid];

    const size_t hb = ((size_t)b * NHn + h) * HWn;
    const size_t vtb = (size_t)(b * NHn + h) * 32;

    short8 qf[4];
    #pragma unroll
    for (int qt = 0; qt < 4; ++qt)
        qf[qt] = *(const short8*)(qs + (hb + (size_t)r * 64 + qt * 16 + col) * 32 + g * 8);

    f32x4 o[4][2];
    #pragma unroll
    for (int qt = 0; qt < 4; ++qt) {
        o[qt][0] = (f32x4){0.f, 0.f, 0.f, 0.f};
        o[qt][1] = (f32x4){0.f, 0.f, 0.f, 0.f};
    }
    float mrow[4] = {-3.0e38f, -3.0e38f, -3.0e38f, -3.0e38f};
    float lrow[4] = {0.f, 0.f, 0.f, 0.f};

    const int* ip = idxp + ((size_t)b * NREGn + r) * TOPKn;

    for (int t = 0; t < TOPKn; ++t) {
        const int rr = ip[t];
        // K fragments: K[kpos=kt*16+col][d=g*8..+7], contiguous 16B
        short8 kf[4];
        #pragma unroll
        for (int kt = 0; kt < 4; ++kt)
            kf[kt] = *(const short8*)(ks + (hb + (size_t)rr * 64 + kt * 16 + col) * 32 + g * 8);
        // V fragments from VT: V^T[d=dt*16+col][kpos=kc*32+g*8..+7], 16B
        short8 vf[2][2];
        #pragma unroll
        for (int dt = 0; dt < 2; ++dt)
            #pragma unroll
            for (int kc = 0; kc < 2; ++kc)
                vf[dt][kc] = *(const short8*)(vt + (vtb + dt * 16 + col) * HWn
                                              + (size_t)rr * 64 + kc * 32 + g * 8);

        // S^T tiles: D[m=kpos=kt*16+g*4+reg][n=qrow=qt*16+col]
        f32x4 s[4][4];
        #pragma unroll
        for (int qt = 0; qt < 4; ++qt)
            #pragma unroll
            for (int kt = 0; kt < 4; ++kt)
                s[qt][kt] = __builtin_amdgcn_mfma_f32_16x16x32_bf16(
                    kf[kt], qf[qt], (f32x4){0.f, 0.f, 0.f, 0.f}, 0, 0, 0);

        #pragma unroll
        for (int qt = 0; qt < 4; ++qt) {
            #pragma unroll
            for (int kt = 0; kt < 4; ++kt)
                #pragma unroll
                for (int e = 0; e < 4; ++e)
                    s[qt][kt][e] *= SCALEf;
            float mx = s[qt][0][0];
            #pragma unroll
            for (int kt = 0; kt < 4; ++kt)
                #pragma unroll
                for (int e = 0; e < 4; ++e)
                    mx = fmaxf(mx, s[qt][kt][e]);
            mx = fmaxf(mx, __shfl_xor(mx, 16));
            mx = fmaxf(mx, __shfl_xor(mx, 32));
            const float mnew = fmaxf(mrow[qt], mx);
            const float corr = __expf(mrow[qt] - mnew);
            mrow[qt] = mnew;
            float ps = 0.f;
            #pragma unroll
            for (int kt = 0; kt < 4; ++kt)
                #pragma unroll
                for (int e = 0; e < 4; ++e) {
                    const float p = __expf(s[qt][kt][e] - mnew);
                    s[qt][kt][e] = p; ps += p;
                }
            ps += __shfl_xor(ps, 16);
            ps += __shfl_xor(ps, 32);
            lrow[qt] = lrow[qt] * corr + ps;
            // P -> LDS (bf16, XOR-swizzled rows)
            const int qrow = qt * 16 + col;
            const int sw = (qrow & 7) << 4;
            #pragma unroll
            for (int kt = 0; kt < 4; ++kt) {
                ushort4 pk = make_ushort4(f2b(s[qt][kt][0]), f2b(s[qt][kt][1]),
                                          f2b(s[qt][kt][2]), f2b(s[qt][kt][3]));
                const int byt = (qrow * 128 + kt * 32 + g * 8) ^ sw;
                *(ushort4*)((char*)pw + byt) = pk;
            }
            // rescale O rows (row index of O frag = qt*16 + g*4 + reg)
            #pragma unroll
            for (int reg = 0; reg < 4; ++reg) {
                const float cr = __shfl(corr, g * 4 + reg);
                o[qt][0][reg] *= cr;
                o[qt][1][reg] *= cr;
            }
        }
        // PV: O[m=qrow][n=d] += P[qrow][kpos] * V[kpos][d]
        #pragma unroll
        for (int kc = 0; kc < 2; ++kc)
            #pragma unroll
            for (int qt = 0; qt < 4; ++qt) {
                const int qrow = qt * 16 + col;
                const int byt = (qrow * 128 + kc * 64 + g * 16) ^ ((qrow & 7) << 4);
                const short8 pf = *(const short8*)((const char*)pw + byt);
                o[qt][0] = __builtin_amdgcn_mfma_f32_16x16x32_bf16(pf, vf[0][kc], o[qt][0], 0, 0, 0);
                o[qt][1] = __builtin_amdgcn_mfma_f32_16x16x32_bf16(pf, vf[1][kc], o[qt][1], 0, 0, 0);
            }
    }

    // normalize, bounce O through LDS to get row-contiguous layout
    #pragma unroll
    for (int qt = 0; qt < 4; ++qt) {
        const float linv = 1.0f / lrow[qt];
        #pragma unroll
        for (int reg = 0; reg < 4; ++reg) {
            const float li = __shfl(linv, g * 4 + reg);
            const int row = qt * 16 + g * 4 + reg;
            const int sw = ((row >> 1) & 3) << 4;
            #pragma unroll
            for (int dt = 0; dt < 2; ++dt) {
                const int byt = (row * 64 + (dt * 16 + col) * 2) ^ sw;
                *(ushort*)((char*)pw + byt) = f2b(o[qt][dt][reg] * li);
            }
        }
    }
    // lane = output row (ss within region); add LePE, store 64B contiguous
    const int py = (r / 7) * 8 + (lane >> 3), px = (r % 7) * 8 + (lane & 7);
    const ushort* lp = lep + ((size_t)b * Cn + h * 32) * HWn + py * Wn + px;
    ushort* yp = yt + ((size_t)b * NPn + (size_t)r * 64 + lane) * Cn + h * 32;
    const int swl = ((lane >> 1) & 3) << 4;
    #pragma unroll
    for (int c4 = 0; c4 < 8; ++c4) {
        const int byt = (lane * 64 + c4 * 8) ^ swl;
        const ushort4 ov = *(const ushort4*)((const char*)pw + byt);
        ushort4 w4 = make_ushort4(
            f2b(b2f(ov.x) + b2f(lp[(size_t)(c4 * 4 + 0) * HWn])),
            f2b(b2f(ov.y) + b2f(lp[(size_t)(c4 * 4 + 1) * HWn])),
            f2b(b2f(ov.z) + b2f(lp[(size_t)(c4 * 4 + 2) * HWn])),
            f2b(b2f(ov.w) + b2f(lp[(size_t)(c4 * 4 + 3) * HWn])));
        *(ushort4*)(yp + c4 * 4) = w4;
    }
}

// ---------------------------------------------------------------------------
extern "C" void kernel_launch(void* const* d_in, const int* in_sizes, int n_in,
                              void* d_out, int out_size, void* d_ws, size_t ws_size,
                              hipStream_t stream)
{
    const float* x      = (const float*)d_in[0];
    const float* qkv_w  = (const float*)d_in[1];
    const float* qkv_b  = (const float*)d_in[2];
    const float* lepe_w = (const float*)d_in[3];
    const float* lepe_b = (const float*)d_in[4];
    const float* out_w  = (const float*)d_in[5];
    const float* out_b  = (const float*)d_in[6];
    float* out = (float*)d_out;

    char* ws = (char*)d_ws;
    ushort* XT = (ushort*)(ws);                                  // 26,214,400
    ushort* YT = (ushort*)(ws + 26214400);                       // 26,214,400
    ushort* QS = (ushort*)(ws + 52428800);                       // 25,690,112
    ushort* KS = (ushort*)(ws + 78118912);                       // 25,690,112
    ushort* VT = (ushort*)(ws + 103809024);                      // 25,690,112
    ushort* VP = (ushort*)(ws + 129499136);                      // 25,690,112
    ushort* LB = (ushort*)(ws + 155189248);                      // 25,690,112
    ushort* WQ = (ushort*)(ws + 180879360);                      // 393,216
    ushort* WO = (ushort*)(ws + 181272576);                      // 131,072
    float*  XR = (float*)(ws + 181403648);                       // 802,816
    float*  QR = (float*)(ws + 182206464);                       // 802,816
    float*  KR = (float*)(ws + 183009280);                       // 802,816
    int*   IDX = (int*)(ws + 183812096);                         // 12,544

    fill_pads<<<1024, 256, 0, stream>>>((uint*)XT, (uint*)YT);
    convert_w<<<256, 256, 0, stream>>>(qkv_w, out_w, WQ, WO);
    convert_x<<<dim3(49, 4, 16), 256, 0, stream>>>(x, XT);
    pool_x<<<(Bn * Cn * NREGn + 255) / 256, 256, 0, stream>>>(x, XR);
    qkr_gemm<<<dim3(8, 16), 256, 0, stream>>>(qkv_w, qkv_b, XR, QR, KR);
    routing<<<16, 256, 0, stream>>>(QR, KR, IDX);
    gemm_mfma<0><<<dim3(25, 6, 16), 256, 0, stream>>>(WQ, qkv_b, XT, QS, KS, VT, VP, nullptr);
    lepe<<<dim3(14, 256, 16), 256, 0, stream>>>(VP, lepe_w, lepe_b, LB);
    attention3<<<dim3(49, 2, 16), 256, 0, stream>>>(QS, KS, VT, IDX, LB, YT);
    gemm_mfma<1><<<dim3(25, 2, 16), 256, 0, stream>>>(WO, out_b, YT, nullptr, nullptr, nullptr, nullptr, out);
}

// Round 4
// 330.083 us; speedup vs baseline: 2.7419x; 1.5255x over previous
//
#include <hip/hip_runtime.h>

typedef __attribute__((ext_vector_type(8))) short short8;
typedef __attribute__((ext_vector_type(4))) float f32x4;
typedef unsigned int uint;

constexpr int Bn    = 16;
constexpr int Cn    = 256;
constexpr int Hn    = 56;
constexpr int Wn    = 56;
constexpr int HWn   = Hn * Wn;       // 3136
constexpr int NPn   = 3200;          // padded N (25 * 128)
constexpr int NHn   = 8;
constexpr int RWn   = 7;
constexpr int NREGn = 49;
constexpr int TOPKn = 4;
constexpr float SCALEf = 0.0625f;

__device__ __forceinline__ float b2f(ushort u) { return __builtin_bit_cast(float, (uint)u << 16); }
__device__ __forceinline__ float b2fl(uint u) { return __builtin_bit_cast(float, u << 16); }
__device__ __forceinline__ float b2fh(uint u) { return __builtin_bit_cast(float, u & 0xffff0000u); }
__device__ __forceinline__ ushort f2b(float f) {
    uint u = __builtin_bit_cast(uint, f);
    u = (u + 0x7fffu + ((u >> 16) & 1u)) >> 16;
    return (ushort)u;
}

typedef __attribute__((address_space(3))) uint lds_u32_t;
typedef __attribute__((address_space(1))) const uint glb_u32_t;
__device__ __forceinline__ void gl_lds16(const ushort* g, ushort* l) {
    __builtin_amdgcn_global_load_lds((glb_u32_t*)g, (lds_u32_t*)l, 16, 0, 0);
}

// ---------------------------------------------------------------------------
// fill pad rows (3136..3199) of XT and YT with zeros
// ---------------------------------------------------------------------------
__global__ __launch_bounds__(256)
void fill_pads(uint* __restrict__ xt, uint* __restrict__ yt)
{
    const int gid = blockIdx.x * 256 + threadIdx.x;      // 0..262143
    const int arr = gid >> 17;
    const int e   = gid & 131071;
    const int b   = e >> 13;                              // 8192 uints / batch
    const int off = e & 8191;
    uint* base = arr ? yt : xt;
    base[(size_t)b * (NPn * Cn / 2) + (HWn * Cn / 2) + off] = 0u;
}

// ---------------------------------------------------------------------------
// convert qkv_w (768x256) and out_w (256x256) f32 -> bf16
// ---------------------------------------------------------------------------
__global__ __launch_bounds__(256)
void convert_w(const float* __restrict__ qw, const float* __restrict__ ow,
               ushort* __restrict__ wq, ushort* __restrict__ wo)
{
    const int e = (blockIdx.x * 256 + threadIdx.x) * 4;   // 262144 total
    if (e < 196608) {
        const float4 v = *(const float4*)(qw + e);
        *(ushort4*)(wq + e) = make_ushort4(f2b(v.x), f2b(v.y), f2b(v.z), f2b(v.w));
    } else {
        const int e2 = e - 196608;
        const float4 v = *(const float4*)(ow + e2);
        *(ushort4*)(wo + e2) = make_ushort4(f2b(v.x), f2b(v.y), f2b(v.z), f2b(v.w));
    }
}

// ---------------------------------------------------------------------------
// x (B,256,3136) f32 -> XT (B,3200,256) bf16 (transposed, N-major)
// ---------------------------------------------------------------------------
__global__ __launch_bounds__(256)
void convert_x(const float* __restrict__ x, ushort* __restrict__ xt)
{
    __shared__ float tile[64][65];
    const int p0 = blockIdx.x * 64, c0 = blockIdx.y * 64, b = blockIdx.z;
    const int tid = threadIdx.x;
    #pragma unroll
    for (int it = 0; it < 4; ++it) {
        const int slot = it * 256 + tid;
        const int c = slot >> 4, p4 = (slot & 15) << 2;
        const float4 v = *(const float4*)(x + ((size_t)b * Cn + c0 + c) * HWn + p0 + p4);
        tile[c][p4 + 0] = v.x; tile[c][p4 + 1] = v.y;
        tile[c][p4 + 2] = v.z; tile[c][p4 + 3] = v.w;
    }
    __syncthreads();
    #pragma unroll
    for (int it = 0; it < 4; ++it) {
        const int slot = it * 256 + tid;
        const int p = slot >> 4, c4 = (slot & 15) << 2;
        ushort4 w4 = make_ushort4(f2b(tile[c4 + 0][p]), f2b(tile[c4 + 1][p]),
                                  f2b(tile[c4 + 2][p]), f2b(tile[c4 + 3][p]));
        *(ushort4*)(xt + ((size_t)b * NPn + p0 + p) * Cn + c0 + c4) = w4;
    }
}

// ---------------------------------------------------------------------------
// pool x: (B,256,3136) f32 -> xr (B,256,49) f32  (8x8 region means)
// ---------------------------------------------------------------------------
__global__ __launch_bounds__(256)
void pool_x(const float* __restrict__ x, float* __restrict__ xr)
{
    const int gid = blockIdx.x * 256 + threadIdx.x;
    if (gid >= Bn * Cn * NREGn) return;
    const int r = gid % NREGn;
    const int t = gid / NREGn;
    const int c = t % Cn, b = t / Cn;
    const float* plane = x + ((size_t)b * Cn + c) * HWn + (r / RWn) * 8 * Wn + (r % RWn) * 8;
    float s = 0.f;
    #pragma unroll
    for (int p = 0; p < 8; ++p) {
        const float4 a  = *(const float4*)(plane + p * Wn);
        const float4 b4 = *(const float4*)(plane + p * Wn + 4);
        s += a.x + a.y + a.z + a.w + b4.x + b4.y + b4.z + b4.w;
    }
    xr[gid] = s * (1.0f / 64.0f);
}

// ---------------------------------------------------------------------------
// pooled q_r/k_r in f32 from pooled x: one output per thread, 1568 blocks
// ---------------------------------------------------------------------------
__global__ __launch_bounds__(256)
void qkr_gemm(const float* __restrict__ qw, const float* __restrict__ qb,
              const float* __restrict__ xr, float* __restrict__ qr,
              float* __restrict__ kr)
{
    const int gid = blockIdx.x * 256 + threadIdx.x;    // 401,408 = 16*512*49
    const int j = gid % NREGn;
    const int t = gid / NREGn;
    const int m = t & 511;
    const int b = t >> 9;
    const float* wr = qw + (size_t)m * Cn;
    const float* xb = xr + (size_t)b * Cn * NREGn + j;
    float s = 0.f;
    #pragma unroll 8
    for (int c = 0; c < Cn; ++c)
        s = fmaf(wr[c], xb[c * NREGn], s);
    s += qb[m];
    if (m < Cn) qr[((size_t)b * Cn + m) * NREGn + j] = s;
    else        kr[((size_t)b * Cn + (m - Cn)) * NREGn + j] = s;
}

// ---------------------------------------------------------------------------
// routing: a[i][j] = sum_c qr[b,c,i]*kr[b,c,j]; top-4 per row (f32 exact path)
// ---------------------------------------------------------------------------
__global__ __launch_bounds__(256)
void routing(const float* __restrict__ qr, const float* __restrict__ kr,
             int* __restrict__ idxo)
{
    const int b = blockIdx.x;
    __shared__ float ksh[Cn][NREGn];
    __shared__ float ar[NREGn][NREGn + 1];
    const float* qb = qr + (size_t)b * Cn * NREGn;
    const float* kb = kr + (size_t)b * Cn * NREGn;
    for (int rr = 0; rr < NREGn; ++rr)
        ksh[threadIdx.x][rr] = kb[threadIdx.x * NREGn + rr];
    __syncthreads();
    for (int e = threadIdx.x; e < NREGn * NREGn; e += 256) {
        const int i = e / NREGn, j = e % NREGn;
        float s = 0.f;
        for (int c = 0; c < Cn; ++c)
            s = fmaf(qb[c * NREGn + i], ksh[c][j], s);
        ar[i][j] = s;
    }
    __syncthreads();
    if (threadIdx.x < NREGn) {
        const int i = threadIdx.x;
        float bv0 = -3.0e38f, bv1 = -3.0e38f, bv2 = -3.0e38f, bv3 = -3.0e38f;
        int bi0 = 0, bi1 = 0, bi2 = 0, bi3 = 0;
        for (int j = 0; j < NREGn; ++j) {
            const float v = ar[i][j];
            if (v > bv3) {
                if (v > bv0)      { bv3=bv2; bi3=bi2; bv2=bv1; bi2=bi1; bv1=bv0; bi1=bi0; bv0=v; bi0=j; }
                else if (v > bv1) { bv3=bv2; bi3=bi2; bv2=bv1; bi2=bi1; bv1=v; bi1=j; }
                else if (v > bv2) { bv3=bv2; bi3=bi2; bv2=v; bi2=j; }
                else              { bv3=v; bi3=j; }
            }
        }
        int* o = idxo + ((size_t)b * NREGn + i) * TOPKn;
        o[0] = bi0; o[1] = bi1; o[2] = bi2; o[3] = bi3;
    }
}

// ---------------------------------------------------------------------------
// bf16 MFMA GEMM: D[m][n] = sum_k W[m][k] * XT[n][k], 128x128 tile, 4 waves.
// MODE 0: qkv -> q/k seq layout (B,NH,3136,32) bf16; v -> VT (B,NH,32,3136)
//         transposed seq + VP plane (B,C,HW) bf16 (for LePE)
// MODE 1: out projection -> d_out f32 plane (B,256,HW), n is region-ordered
// ---------------------------------------------------------------------------
template<int MODE>
__global__ __launch_bounds__(256)
void gemm_mfma(const ushort* __restrict__ Wb, const float* __restrict__ bias,
               const ushort* __restrict__ Bt,
               ushort* __restrict__ oq, ushort* __restrict__ ok,
               ushort* __restrict__ ovt, ushort* __restrict__ ovp,
               float* __restrict__ of)
{
    constexpr int K = Cn;
    const int bb = blockIdx.z;
    const int n0 = blockIdx.x * 128;
    const int m0 = blockIdx.y * 128;
    __shared__ ushort As[128 * 32];
    __shared__ ushort Bs[128 * 32];
    const int tid = threadIdx.x;
    const int wid = tid >> 6, lane = tid & 63;
    const int wm = wid >> 1, wn = wid & 1;        // wave quadrant (2x2 of 64x64)
    const ushort* Bb = Bt + (size_t)bb * NPn * K;

    f32x4 acc[4][4];
    #pragma unroll
    for (int i = 0; i < 4; ++i)
        #pragma unroll
        for (int j = 0; j < 4; ++j)
            acc[i][j] = (f32x4){0.f, 0.f, 0.f, 0.f};

    const int cA = wid * 64 + lane;               // chunk id 0..255
    const int rowA = cA >> 2, koffA = (cA & 3) << 3;

    for (int k0 = 0; k0 < K; k0 += 32) {
        gl_lds16(Wb + (size_t)(m0 + rowA) * K + k0 + koffA, As + wid * 512);
        gl_lds16(Wb + (size_t)(m0 + rowA + 64) * K + k0 + koffA, As + 2048 + wid * 512);
        gl_lds16(Bb + (size_t)(n0 + rowA) * K + k0 + koffA, Bs + wid * 512);
        gl_lds16(Bb + (size_t)(n0 + rowA + 64) * K + k0 + koffA, Bs + 2048 + wid * 512);
        __syncthreads();
        short8 a[4], b[4];
        #pragma unroll
        for (int i = 0; i < 4; ++i)
            a[i] = *(const short8*)(As + (wm * 64 + i * 16 + (lane & 15)) * 32 + ((lane >> 4) << 3));
        #pragma unroll
        for (int j = 0; j < 4; ++j)
            b[j] = *(const short8*)(Bs + (wn * 64 + j * 16 + (lane & 15)) * 32 + ((lane >> 4) << 3));
        #pragma unroll
        for (int i = 0; i < 4; ++i)
            #pragma unroll
            for (int j = 0; j < 4; ++j)
                acc[i][j] = __builtin_amdgcn_mfma_f32_16x16x32_bf16(a[i], b[j], acc[i][j], 0, 0, 0);
        __syncthreads();
    }

    if (MODE == 0) {
        #pragma unroll
        for (int i = 0; i < 4; ++i) {
            const int m_base = m0 + wm * 64 + i * 16;
            const int which = m_base >> 8;                       // 0=q 1=k 2=v
            const int hh = (m_base >> 5) & 7;
            const int db = (m_base & 31) + ((lane >> 4) << 2);   // 0..28
            const int cb = (m_base & 255) + ((lane >> 4) << 2);
            const float4 b4 = *(const float4*)(bias + m_base + ((lane >> 4) << 2));
            #pragma unroll
            for (int j = 0; j < 4; ++j) {
                const int n = n0 + wn * 64 + j * 16 + (lane & 15);
                if (n < HWn) {
                    const int py = n / 56, px = n % 56;
                    const int rr = (py >> 3) * 7 + (px >> 3);
                    const int ss = ((py & 7) << 3) + (px & 7);
                    ushort4 w4 = make_ushort4(f2b(acc[i][j][0] + b4.x), f2b(acc[i][j][1] + b4.y),
                                              f2b(acc[i][j][2] + b4.z), f2b(acc[i][j][3] + b4.w));
                    if (which < 2) {
                        ushort* op = (which == 0) ? oq : ok;
                        *(ushort4*)(op + (((size_t)bb * NHn + hh) * HWn + rr * 64 + ss) * 32 + db) = w4;
                    } else {
                        const size_t vtb = ((size_t)(bb * NHn + hh) * 32 + db) * HWn + rr * 64 + ss;
                        ovt[vtb + 0 * HWn] = w4.x;
                        ovt[vtb + 1 * HWn] = w4.y;
                        ovt[vtb + 2 * HWn] = w4.z;
                        ovt[vtb + 3 * HWn] = w4.w;
                        ovp[((size_t)bb * Cn + cb + 0) * HWn + n] = w4.x;
                        ovp[((size_t)bb * Cn + cb + 1) * HWn + n] = w4.y;
                        ovp[((size_t)bb * Cn + cb + 2) * HWn + n] = w4.z;
                        ovp[((size_t)bb * Cn + cb + 3) * HWn + n] = w4.w;
                    }
                }
            }
        }
    } else {
        #pragma unroll
        for (int i = 0; i < 4; ++i) {
            const int mb = m0 + wm * 64 + i * 16 + ((lane >> 4) << 2);
            const float4 b4 = *(const float4*)(bias + mb);
            #pragma unroll
            for (int j = 0; j < 4; ++j) {
                const int n = n0 + wn * 64 + j * 16 + (lane & 15);
                if (n < HWn) {
                    const int rr = n >> 6, ss = n & 63;
                    const int py = (rr / 7) * 8 + (ss >> 3);
                    const int px = (rr % 7) * 8 + (ss & 7);
                    float* od = of + ((size_t)bb * Cn + mb) * HWn + py * 56 + px;
                    od[0 * HWn] = acc[i][j][0] + b4.x;
                    od[1 * HWn] = acc[i][j][1] + b4.y;
                    od[2 * HWn] = acc[i][j][2] + b4.z;
                    od[3 * HWn] = acc[i][j][3] + b4.w;
                }
            }
        }
    }
}

// ---------------------------------------------------------------------------
// LePE: depthwise 5x5 SAME conv, 8-wide output strip per thread.
// Per row: 3 aligned loads (uint + uint4 + uint) cover cols px0-2..px0+9.
// ---------------------------------------------------------------------------
__global__ __launch_bounds__(256)
void lepe(const ushort* __restrict__ vpl, const float* __restrict__ lw,
          const float* __restrict__ lb, ushort* __restrict__ lbuf)
{
    const int gid = blockIdx.x * 256 + threadIdx.x;   // 1,605,632 = 4096*392
    const int plane = gid / 392;                      // b*256 + c
    const int within = gid - plane * 392;
    const int row = within / 7;
    const int sx  = within - row * 7;
    const int px0 = sx * 8;
    const int c = plane & 255;
    const ushort* vp = vpl + (size_t)plane * HWn;
    const float* wc = lw + c * 25;

    float wreg[25];
    #pragma unroll
    for (int i = 0; i < 25; ++i) wreg[i] = wc[i];

    float acc[8];
    const float bias = lb[c];
    #pragma unroll
    for (int j = 0; j < 8; ++j) acc[j] = bias;

    #pragma unroll
    for (int kh = 0; kh < 5; ++kh) {
        const int iy = row + kh - 2;
        if (iy < 0 || iy >= Hn) continue;
        const ushort* rp = vp + iy * Wn + px0;        // 16B-aligned
        const uint  a = *(const uint*)(rp - 2);       // cols px0-2, px0-1
        const uint4 M = *(const uint4*)(rp);          // cols px0 .. px0+7
        const uint  e = *(const uint*)(rp + 8);       // cols px0+8, px0+9
        float w[12];
        w[0]  = (px0 >= 2)      ? b2fl(a)   : 0.f;    // col px0-2 (only sx==0 masks)
        w[1]  = (px0 >= 1)      ? b2fh(a)   : 0.f;    // col px0-1
        w[2]  = b2fl(M.x); w[3]  = b2fh(M.x);
        w[4]  = b2fl(M.y); w[5]  = b2fh(M.y);
        w[6]  = b2fl(M.z); w[7]  = b2fh(M.z);
        w[8]  = b2fl(M.w); w[9]  = b2fh(M.w);
        w[10] = (px0 + 8 < Wn)  ? b2fl(e)   : 0.f;    // col px0+8 (only sx==6 masks)
        w[11] = (px0 + 9 < Wn)  ? b2fh(e)   : 0.f;    // col px0+9
        #pragma unroll
        for (int kw = 0; kw < 5; ++kw) {
            const float ww = wreg[kh * 5 + kw];
            #pragma unroll
            for (int j = 0; j < 8; ++j)
                acc[j] = fmaf(w[j + kw], ww, acc[j]);
        }
    }
    ushort* op = lbuf + (size_t)plane * HWn + row * Wn + px0;
    *(ushort4*)(op)     = make_ushort4(f2b(acc[0]), f2b(acc[1]), f2b(acc[2]), f2b(acc[3]));
    *(ushort4*)(op + 4) = make_ushort4(f2b(acc[4]), f2b(acc[5]), f2b(acc[6]), f2b(acc[7]));
}

// ---------------------------------------------------------------------------
// MFMA attention: 4 waves/block, wave = one (b, head, region). Swapped QK^T
// (S^T = mfma(K,Q)) -> near-lane-local softmax -> P via swizzled LDS bounce
// -> PV with V fragments straight from transposed VT. LePE fused; writes YT.
// ---------------------------------------------------------------------------
__global__ __launch_bounds__(256, 2)
void attention3(const ushort* __restrict__ qs, const ushort* __restrict__ ks,
                const ushort* __restrict__ vt, const int* __restrict__ idxp,
                const ushort* __restrict__ lep, ushort* __restrict__ yt)
{
    const int r = blockIdx.x, b = blockIdx.z;
    const int wid = threadIdx.x >> 6, lane = threadIdx.x & 63;
    const int h = blockIdx.y * 4 + wid;
    const int col = lane & 15, g = lane >> 4;
    __shared__ ushort plds_all[4][4096];          // 8KB per wave
    ushort* pw = plds_all[wid];

    const size_t hb = ((size_t)b * NHn + h) * HWn;
    const size_t vtb = (size_t)(b * NHn + h) * 32;

    short8 qf[4];
    #pragma unroll
    for (int qt = 0; qt < 4; ++qt)
        qf[qt] = *(const short8*)(qs + (hb + (size_t)r * 64 + qt * 16 + col) * 32 + g * 8);

    f32x4 o[4][2];
    #pragma unroll
    for (int qt = 0; qt < 4; ++qt) {
        o[qt][0] = (f32x4){0.f, 0.f, 0.f, 0.f};
        o[qt][1] = (f32x4){0.f, 0.f, 0.f, 0.f};
    }
    float mrow[4] = {-3.0e38f, -3.0e38f, -3.0e38f, -3.0e38f};
    float lrow[4] = {0.f, 0.f, 0.f, 0.f};

    const int* ip = idxp + ((size_t)b * NREGn + r) * TOPKn;

    for (int t = 0; t < TOPKn; ++t) {
        const int rr = ip[t];
        short8 kf[4];
        #pragma unroll
        for (int kt = 0; kt < 4; ++kt)
            kf[kt] = *(const short8*)(ks + (hb + (size_t)rr * 64 + kt * 16 + col) * 32 + g * 8);
        short8 vf[2][2];
        #pragma unroll
        for (int dt = 0; dt < 2; ++dt)
            #pragma unroll
            for (int kc = 0; kc < 2; ++kc)
                vf[dt][kc] = *(const short8*)(vt + (vtb + dt * 16 + col) * HWn
                                              + (size_t)rr * 64 + kc * 32 + g * 8);

        f32x4 s[4][4];
        #pragma unroll
        for (int qt = 0; qt < 4; ++qt)
            #pragma unroll
            for (int kt = 0; kt < 4; ++kt)
                s[qt][kt] = __builtin_amdgcn_mfma_f32_16x16x32_bf16(
                    kf[kt], qf[qt], (f32x4){0.f, 0.f, 0.f, 0.f}, 0, 0, 0);

        #pragma unroll
        for (int qt = 0; qt < 4; ++qt) {
            #pragma unroll
            for (int kt = 0; kt < 4; ++kt)
                #pragma unroll
                for (int e = 0; e < 4; ++e)
                    s[qt][kt][e] *= SCALEf;
            float mx = s[qt][0][0];
            #pragma unroll
            for (int kt = 0; kt < 4; ++kt)
                #pragma unroll
                for (int e = 0; e < 4; ++e)
                    mx = fmaxf(mx, s[qt][kt][e]);
            mx = fmaxf(mx, __shfl_xor(mx, 16));
            mx = fmaxf(mx, __shfl_xor(mx, 32));
            const float mnew = fmaxf(mrow[qt], mx);
            const float corr = __expf(mrow[qt] - mnew);
            mrow[qt] = mnew;
            float ps = 0.f;
            #pragma unroll
            for (int kt = 0; kt < 4; ++kt)
                #pragma unroll
                for (int e = 0; e < 4; ++e) {
                    const float p = __expf(s[qt][kt][e] - mnew);
                    s[qt][kt][e] = p; ps += p;
                }
            ps += __shfl_xor(ps, 16);
            ps += __shfl_xor(ps, 32);
            lrow[qt] = lrow[qt] * corr + ps;
            const int qrow = qt * 16 + col;
            const int sw = (qrow & 7) << 4;
            #pragma unroll
            for (int kt = 0; kt < 4; ++kt) {
                ushort4 pk = make_ushort4(f2b(s[qt][kt][0]), f2b(s[qt][kt][1]),
                                          f2b(s[qt][kt][2]), f2b(s[qt][kt][3]));
                const int byt = (qrow * 128 + kt * 32 + g * 8) ^ sw;
                *(ushort4*)((char*)pw + byt) = pk;
            }
            #pragma unroll
            for (int reg = 0; reg < 4; ++reg) {
                const float cr = __shfl(corr, g * 4 + reg);
                o[qt][0][reg] *= cr;
                o[qt][1][reg] *= cr;
            }
        }
        #pragma unroll
        for (int kc = 0; kc < 2; ++kc)
            #pragma unroll
            for (int qt = 0; qt < 4; ++qt) {
                const int qrow = qt * 16 + col;
                const int byt = (qrow * 128 + kc * 64 + g * 16) ^ ((qrow & 7) << 4);
                const short8 pf = *(const short8*)((const char*)pw + byt);
                o[qt][0] = __builtin_amdgcn_mfma_f32_16x16x32_bf16(pf, vf[0][kc], o[qt][0], 0, 0, 0);
                o[qt][1] = __builtin_amdgcn_mfma_f32_16x16x32_bf16(pf, vf[1][kc], o[qt][1], 0, 0, 0);
            }
    }

    #pragma unroll
    for (int qt = 0; qt < 4; ++qt) {
        const float linv = 1.0f / lrow[qt];
        #pragma unroll
        for (int reg = 0; reg < 4; ++reg) {
            const float li = __shfl(linv, g * 4 + reg);
            const int row = qt * 16 + g * 4 + reg;
            const int sw = ((row >> 1) & 3) << 4;
            #pragma unroll
            for (int dt = 0; dt < 2; ++dt) {
                const int byt = (row * 64 + (dt * 16 + col) * 2) ^ sw;
                *(ushort*)((char*)pw + byt) = f2b(o[qt][dt][reg] * li);
            }
        }
    }
    const int py = (r / 7) * 8 + (lane >> 3), px = (r % 7) * 8 + (lane & 7);
    const ushort* lp = lep + ((size_t)b * Cn + h * 32) * HWn + py * Wn + px;
    ushort* yp = yt + ((size_t)b * NPn + (size_t)r * 64 + lane) * Cn + h * 32;
    const int swl = ((lane >> 1) & 3) << 4;
    #pragma unroll
    for (int c4 = 0; c4 < 8; ++c4) {
        const int byt = (lane * 64 + c4 * 8) ^ swl;
        const ushort4 ov = *(const ushort4*)((const char*)pw + byt);
        ushort4 w4 = make_ushort4(
            f2b(b2f(ov.x) + b2f(lp[(size_t)(c4 * 4 + 0) * HWn])),
            f2b(b2f(ov.y) + b2f(lp[(size_t)(c4 * 4 + 1) * HWn])),
            f2b(b2f(ov.z) + b2f(lp[(size_t)(c4 * 4 + 2) * HWn])),
            f2b(b2f(ov.w) + b2f(lp[(size_t)(c4 * 4 + 3) * HWn])));
        *(ushort4*)(yp + c4 * 4) = w4;
    }
}

// ---------------------------------------------------------------------------
extern "C" void kernel_launch(void* const* d_in, const int* in_sizes, int n_in,
                              void* d_out, int out_size, void* d_ws, size_t ws_size,
                              hipStream_t stream)
{
    const float* x      = (const float*)d_in[0];
    const float* qkv_w  = (const float*)d_in[1];
    const float* qkv_b  = (const float*)d_in[2];
    const float* lepe_w = (const float*)d_in[3];
    const float* lepe_b = (const float*)d_in[4];
    const float* out_w  = (const float*)d_in[5];
    const float* out_b  = (const float*)d_in[6];
    float* out = (float*)d_out;

    char* ws = (char*)d_ws;
    ushort* XT = (ushort*)(ws);                                  // 26,214,400
    ushort* YT = (ushort*)(ws + 26214400);                       // 26,214,400
    ushort* QS = (ushort*)(ws + 52428800);                       // 25,690,112
    ushort* KS = (ushort*)(ws + 78118912);                       // 25,690,112
    ushort* VT = (ushort*)(ws + 103809024);                      // 25,690,112
    ushort* VP = (ushort*)(ws + 129499136);                      // 25,690,112
    ushort* LB = (ushort*)(ws + 155189248);                      // 25,690,112
    ushort* WQ = (ushort*)(ws + 180879360);                      // 393,216
    ushort* WO = (ushort*)(ws + 181272576);                      // 131,072
    float*  XR = (float*)(ws + 181403648);                       // 802,816
    float*  QR = (float*)(ws + 182206464);                       // 802,816
    float*  KR = (float*)(ws + 183009280);                       // 802,816
    int*   IDX = (int*)(ws + 183812096);                         // 12,544

    fill_pads<<<1024, 256, 0, stream>>>((uint*)XT, (uint*)YT);
    convert_w<<<256, 256, 0, stream>>>(qkv_w, out_w, WQ, WO);
    convert_x<<<dim3(49, 4, 16), 256, 0, stream>>>(x, XT);
    pool_x<<<(Bn * Cn * NREGn + 255) / 256, 256, 0, stream>>>(x, XR);
    qkr_gemm<<<1568, 256, 0, stream>>>(qkv_w, qkv_b, XR, QR, KR);
    routing<<<16, 256, 0, stream>>>(QR, KR, IDX);
    gemm_mfma<0><<<dim3(25, 6, 16), 256, 0, stream>>>(WQ, qkv_b, XT, QS, KS, VT, VP, nullptr);
    lepe<<<6272, 256, 0, stream>>>(VP, lepe_w, lepe_b, LB);
    attention3<<<dim3(49, 2, 16), 256, 0, stream>>>(QS, KS, VT, IDX, LB, YT);
    gemm_mfma<1><<<dim3(25, 2, 16), 256, 0, stream>>>(WO, out_b, YT, nullptr, nullptr, nullptr, nullptr, out);
}

// Round 5
// 258.383 us; speedup vs baseline: 3.5027x; 1.2775x over previous
//
#include <hip/hip_runtime.h>

typedef __attribute__((ext_vector_type(8))) short short8;
typedef __attribute__((ext_vector_type(4))) float f32x4;
typedef unsigned int uint;

constexpr int Bn    = 16;
constexpr int Cn    = 256;
constexpr int Hn    = 56;
constexpr int Wn    = 56;
constexpr int HWn   = Hn * Wn;       // 3136
constexpr int NPn   = 3200;          // padded N (25 * 128)
constexpr int NHn   = 8;
constexpr int RWn   = 7;
constexpr int NREGn = 49;
constexpr int TOPKn = 4;
// scale folded into stored q: 256^-0.5 * log2(e)  (softmax done in base 2)
constexpr float QKSf = 0.0625f * 1.44269504088896f;

__device__ __forceinline__ float b2f(ushort u) { return __builtin_bit_cast(float, (uint)u << 16); }
__device__ __forceinline__ float b2fl(uint u) { return __builtin_bit_cast(float, u << 16); }
__device__ __forceinline__ float b2fh(uint u) { return __builtin_bit_cast(float, u & 0xffff0000u); }
__device__ __forceinline__ ushort f2b(float f) {
    uint u = __builtin_bit_cast(uint, f);
    u = (u + 0x7fffu + ((u >> 16) & 1u)) >> 16;
    return (ushort)u;
}

typedef __attribute__((address_space(3))) uint lds_u32_t;
typedef __attribute__((address_space(1))) const uint glb_u32_t;
__device__ __forceinline__ void gl_lds16(const ushort* g, ushort* l) {
    __builtin_amdgcn_global_load_lds((glb_u32_t*)g, (lds_u32_t*)l, 16, 0, 0);
}

// ---------------------------------------------------------------------------
// fill pad rows (3136..3199) of XT and YT with zeros
// ---------------------------------------------------------------------------
__global__ __launch_bounds__(256)
void fill_pads(uint* __restrict__ xt, uint* __restrict__ yt)
{
    const int gid = blockIdx.x * 256 + threadIdx.x;      // 0..262143
    const int arr = gid >> 17;
    const int e   = gid & 131071;
    const int b   = e >> 13;                              // 8192 uints / batch
    const int off = e & 8191;
    uint* base = arr ? yt : xt;
    base[(size_t)b * (NPn * Cn / 2) + (HWn * Cn / 2) + off] = 0u;
}

// ---------------------------------------------------------------------------
// convert qkv_w (768x256) and out_w (256x256) f32 -> bf16
// ---------------------------------------------------------------------------
__global__ __launch_bounds__(256)
void convert_w(const float* __restrict__ qw, const float* __restrict__ ow,
               ushort* __restrict__ wq, ushort* __restrict__ wo)
{
    const int e = (blockIdx.x * 256 + threadIdx.x) * 4;   // 262144 total
    if (e < 196608) {
        const float4 v = *(const float4*)(qw + e);
        *(ushort4*)(wq + e) = make_ushort4(f2b(v.x), f2b(v.y), f2b(v.z), f2b(v.w));
    } else {
        const int e2 = e - 196608;
        const float4 v = *(const float4*)(ow + e2);
        *(ushort4*)(wo + e2) = make_ushort4(f2b(v.x), f2b(v.y), f2b(v.z), f2b(v.w));
    }
}

// ---------------------------------------------------------------------------
// x (B,256,3136) f32 -> XT (B,3200,256) bf16 (transposed, N-major)
// ---------------------------------------------------------------------------
__global__ __launch_bounds__(256)
void convert_x(const float* __restrict__ x, ushort* __restrict__ xt)
{
    __shared__ float tile[64][65];
    const int p0 = blockIdx.x * 64, c0 = blockIdx.y * 64, b = blockIdx.z;
    const int tid = threadIdx.x;
    #pragma unroll
    for (int it = 0; it < 4; ++it) {
        const int slot = it * 256 + tid;
        const int c = slot >> 4, p4 = (slot & 15) << 2;
        const float4 v = *(const float4*)(x + ((size_t)b * Cn + c0 + c) * HWn + p0 + p4);
        tile[c][p4 + 0] = v.x; tile[c][p4 + 1] = v.y;
        tile[c][p4 + 2] = v.z; tile[c][p4 + 3] = v.w;
    }
    __syncthreads();
    #pragma unroll
    for (int it = 0; it < 4; ++it) {
        const int slot = it * 256 + tid;
        const int p = slot >> 4, c4 = (slot & 15) << 2;
        ushort4 w4 = make_ushort4(f2b(tile[c4 + 0][p]), f2b(tile[c4 + 1][p]),
                                  f2b(tile[c4 + 2][p]), f2b(tile[c4 + 3][p]));
        *(ushort4*)(xt + ((size_t)b * NPn + p0 + p) * Cn + c0 + c4) = w4;
    }
}

// ---------------------------------------------------------------------------
// pool x: (B,256,3136) f32 -> xr (B,256,49) f32  (8x8 region means)
// ---------------------------------------------------------------------------
__global__ __launch_bounds__(256)
void pool_x(const float* __restrict__ x, float* __restrict__ xr)
{
    const int gid = blockIdx.x * 256 + threadIdx.x;
    if (gid >= Bn * Cn * NREGn) return;
    const int r = gid % NREGn;
    const int t = gid / NREGn;
    const int c = t % Cn, b = t / Cn;
    const float* plane = x + ((size_t)b * Cn + c) * HWn + (r / RWn) * 8 * Wn + (r % RWn) * 8;
    float s = 0.f;
    #pragma unroll
    for (int p = 0; p < 8; ++p) {
        const float4 a  = *(const float4*)(plane + p * Wn);
        const float4 b4 = *(const float4*)(plane + p * Wn + 4);
        s += a.x + a.y + a.z + a.w + b4.x + b4.y + b4.z + b4.w;
    }
    xr[gid] = s * (1.0f / 64.0f);
}

// ---------------------------------------------------------------------------
// pooled q_r/k_r in f32 from pooled x: one output per thread
// ---------------------------------------------------------------------------
__global__ __launch_bounds__(256)
void qkr_gemm(const float* __restrict__ qw, const float* __restrict__ qb,
              const float* __restrict__ xr, float* __restrict__ qr,
              float* __restrict__ kr)
{
    const int gid = blockIdx.x * 256 + threadIdx.x;    // 401,408 = 16*512*49
    const int j = gid % NREGn;
    const int t = gid / NREGn;
    const int m = t & 511;
    const int b = t >> 9;
    const float* wr = qw + (size_t)m * Cn;
    const float* xb = xr + (size_t)b * Cn * NREGn + j;
    float s = 0.f;
    #pragma unroll 8
    for (int c = 0; c < Cn; ++c)
        s = fmaf(wr[c], xb[c * NREGn], s);
    s += qb[m];
    if (m < Cn) qr[((size_t)b * Cn + m) * NREGn + j] = s;
    else        kr[((size_t)b * Cn + (m - Cn)) * NREGn + j] = s;
}

// ---------------------------------------------------------------------------
// routing: a[i][j] = sum_c qr[b,c,i]*kr[b,c,j]; top-4 per row. grid (7,16):
// block = (row-group ig of 7 rows, batch b)
// ---------------------------------------------------------------------------
__global__ __launch_bounds__(256)
void routing(const float* __restrict__ qr, const float* __restrict__ kr,
             int* __restrict__ idxo)
{
    const int ig = blockIdx.x, b = blockIdx.y;
    __shared__ float ksh[Cn][NREGn];        // 50 KB
    __shared__ float qsh[Cn][7];
    __shared__ float ar[7][NREGn];
    const float* qb = qr + (size_t)b * Cn * NREGn;
    const float* kb = kr + (size_t)b * Cn * NREGn;
    for (int rr = 0; rr < NREGn; ++rr)
        ksh[threadIdx.x][rr] = kb[threadIdx.x * NREGn + rr];
    for (int e = threadIdx.x; e < Cn * 7; e += 256)
        qsh[e / 7][e % 7] = qb[(e / 7) * NREGn + ig * 7 + (e % 7)];
    __syncthreads();
    for (int e = threadIdx.x; e < 7 * NREGn; e += 256) {
        const int il = e / NREGn, j = e % NREGn;
        float s = 0.f;
        for (int c = 0; c < Cn; ++c)
            s = fmaf(qsh[c][il], ksh[c][j], s);
        ar[il][j] = s;
    }
    __syncthreads();
    if (threadIdx.x < 7) {
        const int il = threadIdx.x;
        float bv0 = -3.0e38f, bv1 = -3.0e38f, bv2 = -3.0e38f, bv3 = -3.0e38f;
        int bi0 = 0, bi1 = 0, bi2 = 0, bi3 = 0;
        for (int j = 0; j < NREGn; ++j) {
            const float v = ar[il][j];
            if (v > bv3) {
                if (v > bv0)      { bv3=bv2; bi3=bi2; bv2=bv1; bi2=bi1; bv1=bv0; bi1=bi0; bv0=v; bi0=j; }
                else if (v > bv1) { bv3=bv2; bi3=bi2; bv2=bv1; bi2=bi1; bv1=v; bi1=j; }
                else if (v > bv2) { bv3=bv2; bi3=bi2; bv2=v; bi2=j; }
                else              { bv3=v; bi3=j; }
            }
        }
        int* o = idxo + ((size_t)b * NREGn + ig * 7 + il) * TOPKn;
        o[0] = bi0; o[1] = bi1; o[2] = bi2; o[3] = bi3;
    }
}

// ---------------------------------------------------------------------------
// bf16 MFMA GEMM: D[m][n] = sum_k W[m][k] * XT[n][k], 128x128 tile, 4 waves.
// Flat grid + XCD swizzle (m-tiles of one n-tile consecutive per XCD).
// MODE 0: qkv -> q (scaled by QKSf) / k seq layout (B,NH,3136,32) bf16;
//         v -> VT (B,NH,32,HW-regionordered) bf16
// MODE 1: out projection -> d_out f32 plane (B,256,HW)
// ---------------------------------------------------------------------------
template<int MODE>
__global__ __launch_bounds__(256)
void gemm_mfma(const ushort* __restrict__ Wb, const float* __restrict__ bias,
               const ushort* __restrict__ Bt,
               ushort* __restrict__ oq, ushort* __restrict__ ok,
               ushort* __restrict__ ovt, float* __restrict__ of)
{
    constexpr int K = Cn;
    int bb, bx, by;
    {
        const int flat = blockIdx.x;
        if (MODE == 0) {                       // 2400 = 8*300 blocks
            const int sw = (flat & 7) * 300 + (flat >> 3);
            bb = sw / 150; const int r2 = sw % 150; bx = r2 / 6; by = r2 % 6;
        } else {                               // 800 = 8*100 blocks
            const int sw = (flat & 7) * 100 + (flat >> 3);
            bb = sw / 50;  const int r2 = sw % 50;  bx = r2 / 2; by = r2 % 2;
        }
    }
    const int n0 = bx * 128;
    const int m0 = by * 128;
    __shared__ ushort As[128 * 32];
    __shared__ ushort Bs[128 * 32];
    const int tid = threadIdx.x;
    const int wid = tid >> 6, lane = tid & 63;
    const int wm = wid >> 1, wn = wid & 1;        // wave quadrant (2x2 of 64x64)
    const ushort* Bb = Bt + (size_t)bb * NPn * K;

    f32x4 acc[4][4];
    #pragma unroll
    for (int i = 0; i < 4; ++i)
        #pragma unroll
        for (int j = 0; j < 4; ++j)
            acc[i][j] = (f32x4){0.f, 0.f, 0.f, 0.f};

    const int cA = wid * 64 + lane;               // chunk id 0..255
    const int rowA = cA >> 2, koffA = (cA & 3) << 3;

    for (int k0 = 0; k0 < K; k0 += 32) {
        gl_lds16(Wb + (size_t)(m0 + rowA) * K + k0 + koffA, As + wid * 512);
        gl_lds16(Wb + (size_t)(m0 + rowA + 64) * K + k0 + koffA, As + 2048 + wid * 512);
        gl_lds16(Bb + (size_t)(n0 + rowA) * K + k0 + koffA, Bs + wid * 512);
        gl_lds16(Bb + (size_t)(n0 + rowA + 64) * K + k0 + koffA, Bs + 2048 + wid * 512);
        __syncthreads();
        short8 a[4], b[4];
        #pragma unroll
        for (int i = 0; i < 4; ++i)
            a[i] = *(const short8*)(As + (wm * 64 + i * 16 + (lane & 15)) * 32 + ((lane >> 4) << 3));
        #pragma unroll
        for (int j = 0; j < 4; ++j)
            b[j] = *(const short8*)(Bs + (wn * 64 + j * 16 + (lane & 15)) * 32 + ((lane >> 4) << 3));
        #pragma unroll
        for (int i = 0; i < 4; ++i)
            #pragma unroll
            for (int j = 0; j < 4; ++j)
                acc[i][j] = __builtin_amdgcn_mfma_f32_16x16x32_bf16(a[i], b[j], acc[i][j], 0, 0, 0);
        __syncthreads();
    }

    if (MODE == 0) {
        #pragma unroll
        for (int i = 0; i < 4; ++i) {
            const int m_base = m0 + wm * 64 + i * 16;
            const int which = m_base >> 8;                       // 0=q 1=k 2=v
            const int hh = (m_base >> 5) & 7;
            const int db = (m_base & 31) + ((lane >> 4) << 2);   // 0..28
            const float4 b4 = *(const float4*)(bias + m_base + ((lane >> 4) << 2));
            #pragma unroll
            for (int j = 0; j < 4; ++j) {
                const int n = n0 + wn * 64 + j * 16 + (lane & 15);
                if (n < HWn) {
                    const int py = n / 56, px = n % 56;
                    const int rr = (py >> 3) * 7 + (px >> 3);
                    const int ss = ((py & 7) << 3) + (px & 7);
                    if (which == 0) {
                        ushort4 w4 = make_ushort4(
                            f2b((acc[i][j][0] + b4.x) * QKSf), f2b((acc[i][j][1] + b4.y) * QKSf),
                            f2b((acc[i][j][2] + b4.z) * QKSf), f2b((acc[i][j][3] + b4.w) * QKSf));
                        *(ushort4*)(oq + (((size_t)bb * NHn + hh) * HWn + rr * 64 + ss) * 32 + db) = w4;
                    } else if (which == 1) {
                        ushort4 w4 = make_ushort4(f2b(acc[i][j][0] + b4.x), f2b(acc[i][j][1] + b4.y),
                                                  f2b(acc[i][j][2] + b4.z), f2b(acc[i][j][3] + b4.w));
                        *(ushort4*)(ok + (((size_t)bb * NHn + hh) * HWn + rr * 64 + ss) * 32 + db) = w4;
                    } else {
                        const size_t vtb = ((size_t)(bb * NHn + hh) * 32 + db) * HWn + rr * 64 + ss;
                        ovt[vtb + 0 * HWn] = f2b(acc[i][j][0] + b4.x);
                        ovt[vtb + 1 * HWn] = f2b(acc[i][j][1] + b4.y);
                        ovt[vtb + 2 * HWn] = f2b(acc[i][j][2] + b4.z);
                        ovt[vtb + 3 * HWn] = f2b(acc[i][j][3] + b4.w);
                    }
                }
            }
        }
    } else {
        #pragma unroll
        for (int i = 0; i < 4; ++i) {
            const int mb = m0 + wm * 64 + i * 16 + ((lane >> 4) << 2);
            const float4 b4 = *(const float4*)(bias + mb);
            #pragma unroll
            for (int j = 0; j < 4; ++j) {
                const int n = n0 + wn * 64 + j * 16 + (lane & 15);
                if (n < HWn) {
                    const int rr = n >> 6, ss = n & 63;
                    const int py = (rr / 7) * 8 + (ss >> 3);
                    const int px = (rr % 7) * 8 + (ss & 7);
                    float* od = of + ((size_t)bb * Cn + mb) * HWn + py * 56 + px;
                    od[0 * HWn] = acc[i][j][0] + b4.x;
                    od[1 * HWn] = acc[i][j][1] + b4.y;
                    od[2 * HWn] = acc[i][j][2] + b4.z;
                    od[3 * HWn] = acc[i][j][3] + b4.w;
                }
            }
        }
    }
}

// ---------------------------------------------------------------------------
// LePE: depthwise 5x5 SAME conv, 8-wide strip per thread. Input VT and output
// LB are both region-ordered [b][c][rr*64+ss] bf16.
// ---------------------------------------------------------------------------
__global__ __launch_bounds__(256)
void lepe(const ushort* __restrict__ vt, const float* __restrict__ lw,
          const float* __restrict__ lb, ushort* __restrict__ lbuf)
{
    const int gid = blockIdx.x * 256 + threadIdx.x;   // 1,605,632 = 6272*256
    const int plane = gid / 392;                      // b*256 + c
    const int within = gid - plane * 392;
    const int row = within / 7;                       // 0..55
    const int sx  = within - row * 7;                 // 0..6
    const int px0 = sx * 8;
    const int c = plane & 255;
    const ushort* vp = vt + (size_t)plane * HWn;
    const float* wc = lw + c * 25;

    float wreg[25];
    #pragma unroll
    for (int i = 0; i < 25; ++i) wreg[i] = wc[i];

    float acc[8];
    const float bias = lb[c];
    #pragma unroll
    for (int j = 0; j < 8; ++j) acc[j] = bias;

    #pragma unroll
    for (int kh = 0; kh < 5; ++kh) {
        const int iy = row + kh - 2;
        if (iy < 0 || iy >= Hn) continue;
        const int ry = iy >> 3, il = iy & 7;
        const ushort* rp = vp + (ry * 7 + sx) * 64 + il * 8;   // this region's 8 cols
        const uint  a = *(const uint*)(rp - 64 + 6);  // prev region cols 6,7
        const uint4 M = *(const uint4*)(rp);          // cols px0 .. px0+7
        const uint  e = *(const uint*)(rp + 64);      // next region cols 0,1
        float w[12];
        w[0]  = (px0 >= 2)      ? b2fl(a)   : 0.f;
        w[1]  = (px0 >= 1)      ? b2fh(a)   : 0.f;
        w[2]  = b2fl(M.x); w[3]  = b2fh(M.x);
        w[4]  = b2fl(M.y); w[5]  = b2fh(M.y);
        w[6]  = b2fl(M.z); w[7]  = b2fh(M.z);
        w[8]  = b2fl(M.w); w[9]  = b2fh(M.w);
        w[10] = (px0 + 8 < Wn)  ? b2fl(e)   : 0.f;
        w[11] = (px0 + 9 < Wn)  ? b2fh(e)   : 0.f;
        #pragma unroll
        for (int kw = 0; kw < 5; ++kw) {
            const float ww = wreg[kh * 5 + kw];
            #pragma unroll
            for (int j = 0; j < 8; ++j)
                acc[j] = fmaf(w[j + kw], ww, acc[j]);
        }
    }
    ushort* op = lbuf + (size_t)plane * HWn + ((row >> 3) * 7 + sx) * 64 + (row & 7) * 8;
    *(ushort4*)(op)     = make_ushort4(f2b(acc[0]), f2b(acc[1]), f2b(acc[2]), f2b(acc[3]));
    *(ushort4*)(op + 4) = make_ushort4(f2b(acc[4]), f2b(acc[5]), f2b(acc[6]), f2b(acc[7]));
}

// ---------------------------------------------------------------------------
// MFMA attention, flat grid + XCD swizzle (2 batches per XCD for K/V L2 hits).
// Swapped QK^T -> base-2 online softmax (scale folded into Q) -> P via
// swizzled LDS bounce -> PV from transposed VT. LePE fused; writes YT.
// ---------------------------------------------------------------------------
__global__ __launch_bounds__(256, 2)
void attention3(const ushort* __restrict__ qs, const ushort* __restrict__ ks,
                const ushort* __restrict__ vt, const int* __restrict__ idxp,
                const ushort* __restrict__ lep, ushort* __restrict__ yt)
{
    const int flat = blockIdx.x;                  // 1568 = 8*196
    const int sw = (flat & 7) * 196 + (flat >> 3);
    const int b = sw / 98;
    const int rem = sw % 98;
    const int r = rem % 49;
    const int wid = threadIdx.x >> 6, lane = threadIdx.x & 63;
    const int h = (rem / 49) * 4 + wid;
    const int col = lane & 15, g = lane >> 4;
    __shared__ ushort plds_all[4][4096];          // 8KB per wave
    ushort* pw = plds_all[wid];

    const size_t hb = ((size_t)b * NHn + h) * HWn;
    const size_t vtb = (size_t)(b * NHn + h) * 32;

    short8 qf[4];
    #pragma unroll
    for (int qt = 0; qt < 4; ++qt)
        qf[qt] = *(const short8*)(qs + (hb + (size_t)r * 64 + qt * 16 + col) * 32 + g * 8);

    f32x4 o[4][2];
    #pragma unroll
    for (int qt = 0; qt < 4; ++qt) {
        o[qt][0] = (f32x4){0.f, 0.f, 0.f, 0.f};
        o[qt][1] = (f32x4){0.f, 0.f, 0.f, 0.f};
    }
    float mrow[4] = {-3.0e38f, -3.0e38f, -3.0e38f, -3.0e38f};
    float lrow[4] = {0.f, 0.f, 0.f, 0.f};

    const int* ip = idxp + ((size_t)b * NREGn + r) * TOPKn;

    for (int t = 0; t < TOPKn; ++t) {
        const int rr = ip[t];
        short8 kf[4];
        #pragma unroll
        for (int kt = 0; kt < 4; ++kt)
            kf[kt] = *(const short8*)(ks + (hb + (size_t)rr * 64 + kt * 16 + col) * 32 + g * 8);
        short8 vf[2][2];
        #pragma unroll
        for (int dt = 0; dt < 2; ++dt)
            #pragma unroll
            for (int kc = 0; kc < 2; ++kc)
                vf[dt][kc] = *(const short8*)(vt + (vtb + dt * 16 + col) * HWn
                                              + (size_t)rr * 64 + kc * 32 + g * 8);

        f32x4 s[4][4];
        #pragma unroll
        for (int qt = 0; qt < 4; ++qt)
            #pragma unroll
            for (int kt = 0; kt < 4; ++kt)
                s[qt][kt] = __builtin_amdgcn_mfma_f32_16x16x32_bf16(
                    kf[kt], qf[qt], (f32x4){0.f, 0.f, 0.f, 0.f}, 0, 0, 0);

        #pragma unroll
        for (int qt = 0; qt < 4; ++qt) {
            float mx = s[qt][0][0];
            #pragma unroll
            for (int kt = 0; kt < 4; ++kt)
                #pragma unroll
                for (int e = 0; e < 4; ++e)
                    mx = fmaxf(mx, s[qt][kt][e]);
            mx = fmaxf(mx, __shfl_xor(mx, 16));
            mx = fmaxf(mx, __shfl_xor(mx, 32));
            const float mnew = fmaxf(mrow[qt], mx);
            const float corr = exp2f(mrow[qt] - mnew);
            mrow[qt] = mnew;
            float ps = 0.f;
            #pragma unroll
            for (int kt = 0; kt < 4; ++kt)
                #pragma unroll
                for (int e = 0; e < 4; ++e) {
                    const float p = exp2f(s[qt][kt][e] - mnew);
                    s[qt][kt][e] = p; ps += p;
                }
            ps += __shfl_xor(ps, 16);
            ps += __shfl_xor(ps, 32);
            lrow[qt] = lrow[qt] * corr + ps;
            const int qrow = qt * 16 + col;
            const int swz = (qrow & 7) << 4;
            #pragma unroll
            for (int kt = 0; kt < 4; ++kt) {
                ushort4 pk = make_ushort4(f2b(s[qt][kt][0]), f2b(s[qt][kt][1]),
                                          f2b(s[qt][kt][2]), f2b(s[qt][kt][3]));
                const int byt = (qrow * 128 + kt * 32 + g * 8) ^ swz;
                *(ushort4*)((char*)pw + byt) = pk;
            }
            #pragma unroll
            for (int reg = 0; reg < 4; ++reg) {
                const float cr = __shfl(corr, g * 4 + reg);
                o[qt][0][reg] *= cr;
                o[qt][1][reg] *= cr;
            }
        }
        #pragma unroll
        for (int kc = 0; kc < 2; ++kc)
            #pragma unroll
            for (int qt = 0; qt < 4; ++qt) {
                const int qrow = qt * 16 + col;
                const int byt = (qrow * 128 + kc * 64 + g * 16) ^ ((qrow & 7) << 4);
                const short8 pf = *(const short8*)((const char*)pw + byt);
                o[qt][0] = __builtin_amdgcn_mfma_f32_16x16x32_bf16(pf, vf[0][kc], o[qt][0], 0, 0, 0);
                o[qt][1] = __builtin_amdgcn_mfma_f32_16x16x32_bf16(pf, vf[1][kc], o[qt][1], 0, 0, 0);
            }
    }

    #pragma unroll
    for (int qt = 0; qt < 4; ++qt) {
        const float linv = 1.0f / lrow[qt];
        #pragma unroll
        for (int reg = 0; reg < 4; ++reg) {
            const float li = __shfl(linv, g * 4 + reg);
            const int row = qt * 16 + g * 4 + reg;
            const int swz = ((row >> 1) & 3) << 4;
            #pragma unroll
            for (int dt = 0; dt < 2; ++dt) {
                const int byt = (row * 64 + (dt * 16 + col) * 2) ^ swz;
                *(ushort*)((char*)pw + byt) = f2b(o[qt][dt][reg] * li);
            }
        }
    }
    const ushort* lp = lep + ((size_t)b * Cn + h * 32) * HWn + (size_t)r * 64 + lane;
    ushort* yp = yt + ((size_t)b * NPn + (size_t)r * 64 + lane) * Cn + h * 32;
    const int swl = ((lane >> 1) & 3) << 4;
    #pragma unroll
    for (int c4 = 0; c4 < 8; ++c4) {
        const int byt = (lane * 64 + c4 * 8) ^ swl;
        const ushort4 ov = *(const ushort4*)((const char*)pw + byt);
        ushort4 w4 = make_ushort4(
            f2b(b2f(ov.x) + b2f(lp[(size_t)(c4 * 4 + 0) * HWn])),
            f2b(b2f(ov.y) + b2f(lp[(size_t)(c4 * 4 + 1) * HWn])),
            f2b(b2f(ov.z) + b2f(lp[(size_t)(c4 * 4 + 2) * HWn])),
            f2b(b2f(ov.w) + b2f(lp[(size_t)(c4 * 4 + 3) * HWn])));
        *(ushort4*)(yp + c4 * 4) = w4;
    }
}

// ---------------------------------------------------------------------------
extern "C" void kernel_launch(void* const* d_in, const int* in_sizes, int n_in,
                              void* d_out, int out_size, void* d_ws, size_t ws_size,
                              hipStream_t stream)
{
    const float* x      = (const float*)d_in[0];
    const float* qkv_w  = (const float*)d_in[1];
    const float* qkv_b  = (const float*)d_in[2];
    const float* lepe_w = (const float*)d_in[3];
    const float* lepe_b = (const float*)d_in[4];
    const float* out_w  = (const float*)d_in[5];
    const float* out_b  = (const float*)d_in[6];
    float* out = (float*)d_out;

    char* ws = (char*)d_ws;
    ushort* XT = (ushort*)(ws);                                  // 26,214,400
    ushort* YT = (ushort*)(ws + 26214400);                       // 26,214,400
    ushort* QS = (ushort*)(ws + 52428800);                       // 25,690,112
    ushort* KS = (ushort*)(ws + 78118912);                       // 25,690,112
    ushort* VT = (ushort*)(ws + 103809024);                      // 25,690,112
    ushort* LB = (ushort*)(ws + 129499136);                      // 25,690,112
    ushort* WQ = (ushort*)(ws + 155189248);                      // 393,216
    ushort* WO = (ushort*)(ws + 155582464);                      // 131,072
    float*  XR = (float*)(ws + 155713536);                       // 802,816
    float*  QR = (float*)(ws + 156516352);                       // 802,816
    float*  KR = (float*)(ws + 157319168);                       // 802,816
    int*   IDX = (int*)(ws + 158121984);                         // 12,544

    fill_pads<<<1024, 256, 0, stream>>>((uint*)XT, (uint*)YT);
    convert_w<<<256, 256, 0, stream>>>(qkv_w, out_w, WQ, WO);
    convert_x<<<dim3(49, 4, 16), 256, 0, stream>>>(x, XT);
    pool_x<<<(Bn * Cn * NREGn + 255) / 256, 256, 0, stream>>>(x, XR);
    qkr_gemm<<<1568, 256, 0, stream>>>(qkv_w, qkv_b, XR, QR, KR);
    routing<<<dim3(7, 16), 256, 0, stream>>>(QR, KR, IDX);
    gemm_mfma<0><<<2400, 256, 0, stream>>>(WQ, qkv_b, XT, QS, KS, VT, nullptr);
    lepe<<<6272, 256, 0, stream>>>(VT, lepe_w, lepe_b, LB);
    attention3<<<1568, 256, 0, stream>>>(QS, KS, VT, IDX, LB, YT);
    gemm_mfma<1><<<800, 256, 0, stream>>>(WO, out_b, YT, nullptr, nullptr, nullptr, out);
}

// Round 6
// 243.456 us; speedup vs baseline: 3.7175x; 1.0613x over previous
//
#include <hip/hip_runtime.h>

typedef __attribute__((ext_vector_type(8))) short short8;
typedef __attribute__((ext_vector_type(4))) float f32x4;
typedef unsigned int uint;

constexpr int Bn    = 16;
constexpr int Cn    = 256;
constexpr int Hn    = 56;
constexpr int Wn    = 56;
constexpr int HWn   = Hn * Wn;       // 3136
constexpr int NPn   = 3200;          // padded N (25 * 128)
constexpr int NHn   = 8;
constexpr int RWn   = 7;
constexpr int NREGn = 49;
constexpr int TOPKn = 4;
// scale folded into stored q: 256^-0.5 * log2(e)  (softmax done in base 2)
constexpr float QKSf = 0.0625f * 1.44269504088896f;

__device__ __forceinline__ float b2f(ushort u) { return __builtin_bit_cast(float, (uint)u << 16); }
__device__ __forceinline__ float b2fl(uint u) { return __builtin_bit_cast(float, u << 16); }
__device__ __forceinline__ float b2fh(uint u) { return __builtin_bit_cast(float, u & 0xffff0000u); }
// packed f32x2 -> bf16x2 (RNE), single HW instruction
__device__ __forceinline__ uint cvtpk(float lo, float hi) {
    uint r;
    asm("v_cvt_pk_bf16_f32 %0, %1, %2" : "=v"(r) : "v"(lo), "v"(hi));
    return r;
}

typedef __attribute__((address_space(3))) uint lds_u32_t;
typedef __attribute__((address_space(1))) const uint glb_u32_t;
__device__ __forceinline__ void gl_lds16(const ushort* g, ushort* l) {
    __builtin_amdgcn_global_load_lds((glb_u32_t*)g, (lds_u32_t*)l, 16, 0, 0);
}

// ---------------------------------------------------------------------------
// convert qkv_w (768x256) and out_w (256x256) f32 -> bf16
// ---------------------------------------------------------------------------
__global__ __launch_bounds__(256)
void convert_w(const float* __restrict__ qw, const float* __restrict__ ow,
               ushort* __restrict__ wq, ushort* __restrict__ wo)
{
    const int e = (blockIdx.x * 256 + threadIdx.x) * 4;   // 262144 total
    if (e < 196608) {
        const float4 v = *(const float4*)(qw + e);
        uint2 w; w.x = cvtpk(v.x, v.y); w.y = cvtpk(v.z, v.w);
        *(uint2*)(wq + e) = w;
    } else {
        const int e2 = e - 196608;
        const float4 v = *(const float4*)(ow + e2);
        uint2 w; w.x = cvtpk(v.x, v.y); w.y = cvtpk(v.z, v.w);
        *(uint2*)(wo + e2) = w;
    }
}

// ---------------------------------------------------------------------------
// x (B,256,3136) f32 -> XT (B,3200,256) bf16 (transposed, N-major)
// pad rows 3136..3199 never written: they feed only discarded GEMM columns.
// ---------------------------------------------------------------------------
__global__ __launch_bounds__(256)
void convert_x(const float* __restrict__ x, ushort* __restrict__ xt)
{
    __shared__ float tile[64][65];
    const int p0 = blockIdx.x * 64, c0 = blockIdx.y * 64, b = blockIdx.z;
    const int tid = threadIdx.x;
    #pragma unroll
    for (int it = 0; it < 4; ++it) {
        const int slot = it * 256 + tid;
        const int c = slot >> 4, p4 = (slot & 15) << 2;
        const float4 v = *(const float4*)(x + ((size_t)b * Cn + c0 + c) * HWn + p0 + p4);
        tile[c][p4 + 0] = v.x; tile[c][p4 + 1] = v.y;
        tile[c][p4 + 2] = v.z; tile[c][p4 + 3] = v.w;
    }
    __syncthreads();
    #pragma unroll
    for (int it = 0; it < 4; ++it) {
        const int slot = it * 256 + tid;
        const int p = slot >> 4, c4 = (slot & 15) << 2;
        uint2 w;
        w.x = cvtpk(tile[c4 + 0][p], tile[c4 + 1][p]);
        w.y = cvtpk(tile[c4 + 2][p], tile[c4 + 3][p]);
        *(uint2*)(xt + ((size_t)b * NPn + p0 + p) * Cn + c0 + c4) = w;
    }
}

// ---------------------------------------------------------------------------
// pool x: (B,256,3136) f32 -> xr (B,256,49) f32  (8x8 region means)
// ---------------------------------------------------------------------------
__global__ __launch_bounds__(256)
void pool_x(const float* __restrict__ x, float* __restrict__ xr)
{
    const int gid = blockIdx.x * 256 + threadIdx.x;
    if (gid >= Bn * Cn * NREGn) return;
    const int r = gid % NREGn;
    const int t = gid / NREGn;
    const int c = t % Cn, b = t / Cn;
    const float* plane = x + ((size_t)b * Cn + c) * HWn + (r / RWn) * 8 * Wn + (r % RWn) * 8;
    float s = 0.f;
    #pragma unroll
    for (int p = 0; p < 8; ++p) {
        const float4 a  = *(const float4*)(plane + p * Wn);
        const float4 b4 = *(const float4*)(plane + p * Wn + 4);
        s += a.x + a.y + a.z + a.w + b4.x + b4.y + b4.z + b4.w;
    }
    xr[gid] = s * (1.0f / 64.0f);
}

// ---------------------------------------------------------------------------
// pooled q_r/k_r in f32 from pooled x: one output per thread
// ---------------------------------------------------------------------------
__global__ __launch_bounds__(256)
void qkr_gemm(const float* __restrict__ qw, const float* __restrict__ qb,
              const float* __restrict__ xr, float* __restrict__ qr,
              float* __restrict__ kr)
{
    const int gid = blockIdx.x * 256 + threadIdx.x;    // 401,408 = 16*512*49
    const int j = gid % NREGn;
    const int t = gid / NREGn;
    const int m = t & 511;
    const int b = t >> 9;
    const float* wr = qw + (size_t)m * Cn;
    const float* xb = xr + (size_t)b * Cn * NREGn + j;
    float s = 0.f;
    #pragma unroll 8
    for (int c = 0; c < Cn; ++c)
        s = fmaf(wr[c], xb[c * NREGn], s);
    s += qb[m];
    if (m < Cn) qr[((size_t)b * Cn + m) * NREGn + j] = s;
    else        kr[((size_t)b * Cn + (m - Cn)) * NREGn + j] = s;
}

// ---------------------------------------------------------------------------
// routing: a[i][j] = sum_c qr[b,c,i]*kr[b,c,j]; top-4 per row. grid (7,16)
// ---------------------------------------------------------------------------
__global__ __launch_bounds__(256)
void routing(const float* __restrict__ qr, const float* __restrict__ kr,
             int* __restrict__ idxo)
{
    const int ig = blockIdx.x, b = blockIdx.y;
    __shared__ float ksh[Cn][NREGn];        // 50 KB
    __shared__ float qsh[Cn][7];
    __shared__ float ar[7][NREGn];
    const float* qb = qr + (size_t)b * Cn * NREGn;
    const float* kb = kr + (size_t)b * Cn * NREGn;
    for (int e = threadIdx.x; e < Cn * NREGn; e += 256)
        ksh[e / NREGn][e % NREGn] = kb[e];             // coalesced stage
    for (int e = threadIdx.x; e < Cn * 7; e += 256)
        qsh[e / 7][e % 7] = qb[(e / 7) * NREGn + ig * 7 + (e % 7)];
    __syncthreads();
    for (int e = threadIdx.x; e < 7 * NREGn; e += 256) {
        const int il = e / NREGn, j = e % NREGn;
        float s = 0.f;
        for (int c = 0; c < Cn; ++c)
            s = fmaf(qsh[c][il], ksh[c][j], s);
        ar[il][j] = s;
    }
    __syncthreads();
    if (threadIdx.x < 7) {
        const int il = threadIdx.x;
        float bv0 = -3.0e38f, bv1 = -3.0e38f, bv2 = -3.0e38f, bv3 = -3.0e38f;
        int bi0 = 0, bi1 = 0, bi2 = 0, bi3 = 0;
        for (int j = 0; j < NREGn; ++j) {
            const float v = ar[il][j];
            if (v > bv3) {
                if (v > bv0)      { bv3=bv2; bi3=bi2; bv2=bv1; bi2=bi1; bv1=bv0; bi1=bi0; bv0=v; bi0=j; }
                else if (v > bv1) { bv3=bv2; bi3=bi2; bv2=bv1; bi2=bi1; bv1=v; bi1=j; }
                else if (v > bv2) { bv3=bv2; bi3=bi2; bv2=v; bi2=j; }
                else              { bv3=v; bi3=j; }
            }
        }
        int* o = idxo + ((size_t)b * NREGn + ig * 7 + il) * TOPKn;
        o[0] = bi0; o[1] = bi1; o[2] = bi2; o[3] = bi3;
    }
}

// ---------------------------------------------------------------------------
// bf16 MFMA GEMM: D[m][n] = sum_k W[m][k] * XT[n][k], 128x128 tile, 4 waves.
// Flat grid + XCD swizzle. MODE 0: qkv -> q(scaled)/k seq + v -> VT.
// MODE 1: out projection -> d_out f32 plane.
// ---------------------------------------------------------------------------
template<int MODE>
__global__ __launch_bounds__(256)
void gemm_mfma(const ushort* __restrict__ Wb, const float* __restrict__ bias,
               const ushort* __restrict__ Bt,
               ushort* __restrict__ oq, ushort* __restrict__ ok,
               ushort* __restrict__ ovt, float* __restrict__ of)
{
    constexpr int K = Cn;
    int bb, bx, by;
    {
        const int flat = blockIdx.x;
        if (MODE == 0) {                       // 2400 = 8*300 blocks
            const int sw = (flat & 7) * 300 + (flat >> 3);
            bb = sw / 150; const int r2 = sw % 150; bx = r2 / 6; by = r2 % 6;
        } else {                               // 800 = 8*100 blocks
            const int sw = (flat & 7) * 100 + (flat >> 3);
            bb = sw / 50;  const int r2 = sw % 50;  bx = r2 / 2; by = r2 % 2;
        }
    }
    const int n0 = bx * 128;
    const int m0 = by * 128;
    __shared__ ushort As[128 * 32];
    __shared__ ushort Bs[128 * 32];
    const int tid = threadIdx.x;
    const int wid = tid >> 6, lane = tid & 63;
    const int wm = wid >> 1, wn = wid & 1;
    const ushort* Bb = Bt + (size_t)bb * NPn * K;

    f32x4 acc[4][4];
    #pragma unroll
    for (int i = 0; i < 4; ++i)
        #pragma unroll
        for (int j = 0; j < 4; ++j)
            acc[i][j] = (f32x4){0.f, 0.f, 0.f, 0.f};

    const int cA = wid * 64 + lane;
    const int rowA = cA >> 2, koffA = (cA & 3) << 3;

    for (int k0 = 0; k0 < K; k0 += 32) {
        gl_lds16(Wb + (size_t)(m0 + rowA) * K + k0 + koffA, As + wid * 512);
        gl_lds16(Wb + (size_t)(m0 + rowA + 64) * K + k0 + koffA, As + 2048 + wid * 512);
        gl_lds16(Bb + (size_t)(n0 + rowA) * K + k0 + koffA, Bs + wid * 512);
        gl_lds16(Bb + (size_t)(n0 + rowA + 64) * K + k0 + koffA, Bs + 2048 + wid * 512);
        __syncthreads();
        short8 a[4], b[4];
        #pragma unroll
        for (int i = 0; i < 4; ++i)
            a[i] = *(const short8*)(As + (wm * 64 + i * 16 + (lane & 15)) * 32 + ((lane >> 4) << 3));
        #pragma unroll
        for (int j = 0; j < 4; ++j)
            b[j] = *(const short8*)(Bs + (wn * 64 + j * 16 + (lane & 15)) * 32 + ((lane >> 4) << 3));
        #pragma unroll
        for (int i = 0; i < 4; ++i)
            #pragma unroll
            for (int j = 0; j < 4; ++j)
                acc[i][j] = __builtin_amdgcn_mfma_f32_16x16x32_bf16(a[i], b[j], acc[i][j], 0, 0, 0);
        __syncthreads();
    }

    if (MODE == 0) {
        #pragma unroll
        for (int i = 0; i < 4; ++i) {
            const int m_base = m0 + wm * 64 + i * 16;
            const int which = m_base >> 8;                       // 0=q 1=k 2=v
            const int hh = (m_base >> 5) & 7;
            const int db = (m_base & 31) + ((lane >> 4) << 2);   // 0..28
            const float4 b4 = *(const float4*)(bias + m_base + ((lane >> 4) << 2));
            #pragma unroll
            for (int j = 0; j < 4; ++j) {
                const int n = n0 + wn * 64 + j * 16 + (lane & 15);
                if (n < HWn) {
                    const int py = n / 56, px = n % 56;
                    const int rr = (py >> 3) * 7 + (px >> 3);
                    const int ss = ((py & 7) << 3) + (px & 7);
                    if (which == 0) {
                        uint2 w;
                        w.x = cvtpk((acc[i][j][0] + b4.x) * QKSf, (acc[i][j][1] + b4.y) * QKSf);
                        w.y = cvtpk((acc[i][j][2] + b4.z) * QKSf, (acc[i][j][3] + b4.w) * QKSf);
                        *(uint2*)(oq + (((size_t)bb * NHn + hh) * HWn + rr * 64 + ss) * 32 + db) = w;
                    } else if (which == 1) {
                        uint2 w;
                        w.x = cvtpk(acc[i][j][0] + b4.x, acc[i][j][1] + b4.y);
                        w.y = cvtpk(acc[i][j][2] + b4.z, acc[i][j][3] + b4.w);
                        *(uint2*)(ok + (((size_t)bb * NHn + hh) * HWn + rr * 64 + ss) * 32 + db) = w;
                    } else {
                        const size_t vtb = ((size_t)(bb * NHn + hh) * 32 + db) * HWn + rr * 64 + ss;
                        const uint lo = cvtpk(acc[i][j][0] + b4.x, acc[i][j][1] + b4.y);
                        const uint hi = cvtpk(acc[i][j][2] + b4.z, acc[i][j][3] + b4.w);
                        ovt[vtb + 0 * HWn] = (ushort)lo;
                        ovt[vtb + 1 * HWn] = (ushort)(lo >> 16);
                        ovt[vtb + 2 * HWn] = (ushort)hi;
                        ovt[vtb + 3 * HWn] = (ushort)(hi >> 16);
                    }
                }
            }
        }
    } else {
        #pragma unroll
        for (int i = 0; i < 4; ++i) {
            const int mb = m0 + wm * 64 + i * 16 + ((lane >> 4) << 2);
            const float4 b4 = *(const float4*)(bias + mb);
            #pragma unroll
            for (int j = 0; j < 4; ++j) {
                const int n = n0 + wn * 64 + j * 16 + (lane & 15);
                if (n < HWn) {
                    const int rr = n >> 6, ss = n & 63;
                    const int py = (rr / 7) * 8 + (ss >> 3);
                    const int px = (rr % 7) * 8 + (ss & 7);
                    float* od = of + ((size_t)bb * Cn + mb) * HWn + py * 56 + px;
                    od[0 * HWn] = acc[i][j][0] + b4.x;
                    od[1 * HWn] = acc[i][j][1] + b4.y;
                    od[2 * HWn] = acc[i][j][2] + b4.z;
                    od[3 * HWn] = acc[i][j][3] + b4.w;
                }
            }
        }
    }
}

// ---------------------------------------------------------------------------
// LePE: depthwise 5x5 SAME conv, 8-wide strip per thread, region-ordered I/O.
// ---------------------------------------------------------------------------
__global__ __launch_bounds__(256)
void lepe(const ushort* __restrict__ vt, const float* __restrict__ lw,
          const float* __restrict__ lb, ushort* __restrict__ lbuf)
{
    const int gid = blockIdx.x * 256 + threadIdx.x;   // 1,605,632 = 6272*256
    const int plane = gid / 392;                      // b*256 + c
    const int within = gid - plane * 392;
    const int row = within / 7;                       // 0..55
    const int sx  = within - row * 7;                 // 0..6
    const int px0 = sx * 8;
    const int c = plane & 255;
    const ushort* vp = vt + (size_t)plane * HWn;
    const float* wc = lw + c * 25;

    float wreg[25];
    #pragma unroll
    for (int i = 0; i < 25; ++i) wreg[i] = wc[i];

    float acc[8];
    const float bias = lb[c];
    #pragma unroll
    for (int j = 0; j < 8; ++j) acc[j] = bias;

    #pragma unroll
    for (int kh = 0; kh < 5; ++kh) {
        const int iy = row + kh - 2;
        if (iy < 0 || iy >= Hn) continue;
        const int ry = iy >> 3, il = iy & 7;
        const ushort* rp = vp + (ry * 7 + sx) * 64 + il * 8;
        const uint  a = *(const uint*)(rp - 64 + 6);
        const uint4 M = *(const uint4*)(rp);
        const uint  e = *(const uint*)(rp + 64);
        float w[12];
        w[0]  = (px0 >= 2)      ? b2fl(a)   : 0.f;
        w[1]  = (px0 >= 1)      ? b2fh(a)   : 0.f;
        w[2]  = b2fl(M.x); w[3]  = b2fh(M.x);
        w[4]  = b2fl(M.y); w[5]  = b2fh(M.y);
        w[6]  = b2fl(M.z); w[7]  = b2fh(M.z);
        w[8]  = b2fl(M.w); w[9]  = b2fh(M.w);
        w[10] = (px0 + 8 < Wn)  ? b2fl(e)   : 0.f;
        w[11] = (px0 + 9 < Wn)  ? b2fh(e)   : 0.f;
        #pragma unroll
        for (int kw = 0; kw < 5; ++kw) {
            const float ww = wreg[kh * 5 + kw];
            #pragma unroll
            for (int j = 0; j < 8; ++j)
                acc[j] = fmaf(w[j + kw], ww, acc[j]);
        }
    }
    ushort* op = lbuf + (size_t)plane * HWn + ((row >> 3) * 7 + sx) * 64 + (row & 7) * 8;
    uint2 wa, wb;
    wa.x = cvtpk(acc[0], acc[1]); wa.y = cvtpk(acc[2], acc[3]);
    wb.x = cvtpk(acc[4], acc[5]); wb.y = cvtpk(acc[6], acc[7]);
    *(uint2*)(op)     = wa;
    *(uint2*)(op + 4) = wb;
}

// ---------------------------------------------------------------------------
// MFMA attention, XCD-swizzled grid. Swapped QK^T, base-2 online softmax with
// defer-max (THR=8), K/V fragment double-buffering across regions, cvt_pk
// bf16 packing, P via swizzled LDS bounce, PV from VT. LePE fused -> YT.
// ---------------------------------------------------------------------------
__global__ __launch_bounds__(256, 2)
void attention3(const ushort* __restrict__ qs, const ushort* __restrict__ ks,
                const ushort* __restrict__ vt, const int* __restrict__ idxp,
                const ushort* __restrict__ lep, ushort* __restrict__ yt)
{
    const int flat = blockIdx.x;                  // 1568 = 8*196
    const int sw = (flat & 7) * 196 + (flat >> 3);
    const int b = sw / 98;
    const int rem = sw % 98;
    const int r = rem % 49;
    const int wid = threadIdx.x >> 6, lane = threadIdx.x & 63;
    const int h = (rem / 49) * 4 + wid;
    const int col = lane & 15, g = lane >> 4;
    __shared__ ushort plds_all[4][4096];          // 8KB per wave
    ushort* pw = plds_all[wid];

    const size_t hb = ((size_t)b * NHn + h) * HWn;
    const size_t vtb = (size_t)(b * NHn + h) * 32;

    short8 qf[4];
    #pragma unroll
    for (int qt = 0; qt < 4; ++qt)
        qf[qt] = *(const short8*)(qs + (hb + (size_t)r * 64 + qt * 16 + col) * 32 + g * 8);

    f32x4 o[4][2];
    #pragma unroll
    for (int qt = 0; qt < 4; ++qt) {
        o[qt][0] = (f32x4){0.f, 0.f, 0.f, 0.f};
        o[qt][1] = (f32x4){0.f, 0.f, 0.f, 0.f};
    }
    float mrow[4] = {-3.0e38f, -3.0e38f, -3.0e38f, -3.0e38f};
    float lrow[4] = {0.f, 0.f, 0.f, 0.f};

    const int* ip = idxp + ((size_t)b * NREGn + r) * TOPKn;
    const int4 i4 = *(const int4*)ip;
    const int idxs[4] = {i4.x, i4.y, i4.z, i4.w};

    short8 kfA[4], vfA[4];   // vf[dt*2+kc]
    {
        const int rr = idxs[0];
        #pragma unroll
        for (int kt = 0; kt < 4; ++kt)
            kfA[kt] = *(const short8*)(ks + (hb + (size_t)rr * 64 + kt * 16 + col) * 32 + g * 8);
        #pragma unroll
        for (int dt = 0; dt < 2; ++dt)
            #pragma unroll
            for (int kc = 0; kc < 2; ++kc)
                vfA[dt * 2 + kc] = *(const short8*)(vt + (vtb + dt * 16 + col) * HWn
                                                    + (size_t)rr * 64 + kc * 32 + g * 8);
    }

    #pragma unroll
    for (int t = 0; t < TOPKn; ++t) {
        short8 kfB[4], vfB[4];
        if (t < 3) {   // prefetch next region while computing this one
            const int rr = idxs[t + 1];
            #pragma unroll
            for (int kt = 0; kt < 4; ++kt)
                kfB[kt] = *(const short8*)(ks + (hb + (size_t)rr * 64 + kt * 16 + col) * 32 + g * 8);
            #pragma unroll
            for (int dt = 0; dt < 2; ++dt)
                #pragma unroll
                for (int kc = 0; kc < 2; ++kc)
                    vfB[dt * 2 + kc] = *(const short8*)(vt + (vtb + dt * 16 + col) * HWn
                                                         + (size_t)rr * 64 + kc * 32 + g * 8);
        }

        #pragma unroll
        for (int qt = 0; qt < 4; ++qt) {
            f32x4 s[4];
            #pragma unroll
            for (int kt = 0; kt < 4; ++kt)
                s[kt] = __builtin_amdgcn_mfma_f32_16x16x32_bf16(
                    kfA[kt], qf[qt], (f32x4){0.f, 0.f, 0.f, 0.f}, 0, 0, 0);

            float mx = s[0][0];
            #pragma unroll
            for (int kt = 0; kt < 4; ++kt)
                #pragma unroll
                for (int e = 0; e < 4; ++e)
                    mx = fmaxf(mx, s[kt][e]);
            mx = fmaxf(mx, __shfl_xor(mx, 16));
            mx = fmaxf(mx, __shfl_xor(mx, 32));
            // defer-max: only rescale when the running max grew by > 8 (log2)
            if (!__all(mx - mrow[qt] <= 8.f)) {
                const float mnew = fmaxf(mrow[qt], mx);
                const float corr = exp2f(mrow[qt] - mnew);
                mrow[qt] = mnew;
                lrow[qt] *= corr;
                #pragma unroll
                for (int reg = 0; reg < 4; ++reg) {
                    const float cr = __shfl(corr, g * 4 + reg);
                    o[qt][0][reg] *= cr;
                    o[qt][1][reg] *= cr;
                }
            }
            float ps = 0.f;
            #pragma unroll
            for (int kt = 0; kt < 4; ++kt)
                #pragma unroll
                for (int e = 0; e < 4; ++e) {
                    const float p = exp2f(s[kt][e] - mrow[qt]);
                    s[kt][e] = p; ps += p;
                }
            ps += __shfl_xor(ps, 16);
            ps += __shfl_xor(ps, 32);
            lrow[qt] += ps;
            const int qrow = qt * 16 + col;
            const int swz = (qrow & 7) << 4;
            #pragma unroll
            for (int kt = 0; kt < 4; ++kt) {
                uint2 pk;
                pk.x = cvtpk(s[kt][0], s[kt][1]);
                pk.y = cvtpk(s[kt][2], s[kt][3]);
                const int byt = (qrow * 128 + kt * 32 + g * 8) ^ swz;
                *(uint2*)((char*)pw + byt) = pk;
            }
        }

        #pragma unroll
        for (int kc = 0; kc < 2; ++kc)
            #pragma unroll
            for (int qt = 0; qt < 4; ++qt) {
                const int qrow = qt * 16 + col;
                const int byt = (qrow * 128 + kc * 64 + g * 16) ^ ((qrow & 7) << 4);
                const short8 pf = *(const short8*)((const char*)pw + byt);
                o[qt][0] = __builtin_amdgcn_mfma_f32_16x16x32_bf16(pf, vfA[0 * 2 + kc], o[qt][0], 0, 0, 0);
                o[qt][1] = __builtin_amdgcn_mfma_f32_16x16x32_bf16(pf, vfA[1 * 2 + kc], o[qt][1], 0, 0, 0);
            }

        if (t < 3) {
            #pragma unroll
            for (int i = 0; i < 4; ++i) { kfA[i] = kfB[i]; vfA[i] = vfB[i]; }
        }
    }

    // normalize, bounce O through LDS to row-contiguous layout
    #pragma unroll
    for (int qt = 0; qt < 4; ++qt) {
        const float linv = 1.0f / lrow[qt];
        #pragma unroll
        for (int reg = 0; reg < 4; ++reg) {
            const float li = __shfl(linv, g * 4 + reg);
            const int row = qt * 16 + g * 4 + reg;
            const int swz = ((row >> 1) & 3) << 4;
            const uint pk = cvtpk(o[qt][0][reg] * li, o[qt][1][reg] * li);
            const int byt0 = (row * 64 + col * 2) ^ swz;
            const int byt1 = (row * 64 + (16 + col) * 2) ^ swz;
            *(ushort*)((char*)pw + byt0) = (ushort)pk;
            *(ushort*)((char*)pw + byt1) = (ushort)(pk >> 16);
        }
    }
    const ushort* lp = lep + ((size_t)b * Cn + h * 32) * HWn + (size_t)r * 64 + lane;
    ushort* yp = yt + ((size_t)b * NPn + (size_t)r * 64 + lane) * Cn + h * 32;
    const int swl = ((lane >> 1) & 3) << 4;
    #pragma unroll
    for (int c4 = 0; c4 < 8; ++c4) {
        const int byt = (lane * 64 + c4 * 8) ^ swl;
        const ushort4 ov = *(const ushort4*)((const char*)pw + byt);
        const float a0 = b2f(ov.x) + b2f(lp[(size_t)(c4 * 4 + 0) * HWn]);
        const float a1 = b2f(ov.y) + b2f(lp[(size_t)(c4 * 4 + 1) * HWn]);
        const float a2 = b2f(ov.z) + b2f(lp[(size_t)(c4 * 4 + 2) * HWn]);
        const float a3 = b2f(ov.w) + b2f(lp[(size_t)(c4 * 4 + 3) * HWn]);
        uint2 w4; w4.x = cvtpk(a0, a1); w4.y = cvtpk(a2, a3);
        *(uint2*)(yp + c4 * 4) = w4;
    }
}

// ---------------------------------------------------------------------------
extern "C" void kernel_launch(void* const* d_in, const int* in_sizes, int n_in,
                              void* d_out, int out_size, void* d_ws, size_t ws_size,
                              hipStream_t stream)
{
    const float* x      = (const float*)d_in[0];
    const float* qkv_w  = (const float*)d_in[1];
    const float* qkv_b  = (const float*)d_in[2];
    const float* lepe_w = (const float*)d_in[3];
    const float* lepe_b = (const float*)d_in[4];
    const float* out_w  = (const float*)d_in[5];
    const float* out_b  = (const float*)d_in[6];
    float* out = (float*)d_out;

    char* ws = (char*)d_ws;
    ushort* XT = (ushort*)(ws);                                  // 26,214,400
    ushort* YT = (ushort*)(ws + 26214400);                       // 26,214,400
    ushort* QS = (ushort*)(ws + 52428800);                       // 25,690,112
    ushort* KS = (ushort*)(ws + 78118912);                       // 25,690,112
    ushort* VT = (ushort*)(ws + 103809024);                      // 25,690,112
    ushort* LB = (ushort*)(ws + 129499136);                      // 25,690,112
    ushort* WQ = (ushort*)(ws + 155189248);                      // 393,216
    ushort* WO = (ushort*)(ws + 155582464);                      // 131,072
    float*  XR = (float*)(ws + 155713536);                       // 802,816
    float*  QR = (float*)(ws + 156516352);                       // 802,816
    float*  KR = (float*)(ws + 157319168);                       // 802,816
    int*   IDX = (int*)(ws + 158121984);                         // 12,544

    convert_w<<<256, 256, 0, stream>>>(qkv_w, out_w, WQ, WO);
    convert_x<<<dim3(49, 4, 16), 256, 0, stream>>>(x, XT);
    pool_x<<<(Bn * Cn * NREGn + 255) / 256, 256, 0, stream>>>(x, XR);
    qkr_gemm<<<1568, 256, 0, stream>>>(qkv_w, qkv_b, XR, QR, KR);
    routing<<<dim3(7, 16), 256, 0, stream>>>(QR, KR, IDX);
    gemm_mfma<0><<<2400, 256, 0, stream>>>(WQ, qkv_b, XT, QS, KS, VT, nullptr);
    lepe<<<6272, 256, 0, stream>>>(VT, lepe_w, lepe_b, LB);
    attention3<<<1568, 256, 0, stream>>>(QS, KS, VT, IDX, LB, YT);
    gemm_mfma<1><<<800, 256, 0, stream>>>(WO, out_b, YT, nullptr, nullptr, nullptr, out);
}